// Round 7
// baseline (2293.871 us; speedup 1.0000x reference)
//
#include <hip/hip_runtime.h>
#include <stdint.h>

#define HIDDEN 4096
#define INTER  11008
#define NTOK   8192   // B*S = 4*2048
#define WROW   22016  // 2*INTER, qw_gu row length in u32

typedef __bf16 bf16;
typedef __bf16 bf16x8 __attribute__((ext_vector_type(8)));
typedef _Float16 f16;
typedef _Float16 f16x2 __attribute__((ext_vector_type(2)));
typedef _Float16 f16x8 __attribute__((ext_vector_type(8)));
typedef float  f32x4  __attribute__((ext_vector_type(4)));

__device__ __forceinline__ void gload16(const void* g, void* l) {
  __builtin_amdgcn_global_load_lds(
      (const __attribute__((address_space(1))) void*)g,
      (__attribute__((address_space(3))) void*)l, 16, 0, 0);
}
__device__ __forceinline__ void gload4(const void* g, void* l) {
  __builtin_amdgcn_global_load_lds(
      (const __attribute__((address_space(1))) void*)g,
      (__attribute__((address_space(3))) void*)l, 4, 0, 0);
}

// ---------------- x: f32 -> f16 ----------------
__global__ __launch_bounds__(256) void cvt_f16_kernel(const float* __restrict__ x,
                                                      f16* __restrict__ y) {
  const int i = (blockIdx.x * 256 + threadIdx.x) * 8;
  f32x4 a = *(const f32x4*)(x + i);
  f32x4 b = *(const f32x4*)(x + i + 4);
  f16x8 v;
#pragma unroll
  for (int e = 0; e < 4; ++e) { v[e] = (f16)a[e]; v[e + 4] = (f16)b[e]; }
  *(f16x8*)(y + i) = v;
}

// ---------------- spak: per (group, interleaved-col) (s2, k2) f16x2 pairs ----
// layout: u32 spak[(g*22016 + n)*2 + {0: (s,s), 1: (1025+z, 1025+z)}]
__global__ __launch_bounds__(256) void spak_kernel(const uint32_t* __restrict__ qz,
                                                   const float* __restrict__ sc,
                                                   uint32_t* __restrict__ outp) {
  const int idx = blockIdx.x * 256 + threadIdx.x;  // g*22016 + n
  const int gq = idx / WROW;
  const int n = idx - gq * WROW;
  const int grp = n >> 5, win = n & 31;
  const int jg = (win < 16) ? grp * 16 + win : INTER + grp * 16 + (win - 16);
  const float s = sc[(size_t)gq * WROW + jg];
  const uint32_t z = (qz[(size_t)gq * (WROW / 8) + (jg >> 3)] >> ((jg & 7) * 4)) & 15u;
  union { f16 h[2]; uint32_t u; } a, b;
  a.h[0] = (f16)s; a.h[1] = (f16)s;
  b.h[0] = (f16)(float)(1025u + z); b.h[1] = b.h[0];
  outp[(size_t)idx * 2 + 0] = a.u;
  outp[(size_t)idx * 2 + 1] = b.u;
}

// ---------------- GPTQ dequant (W2) -> W^T [J][Kout] bf16 (unchanged) -------
__global__ __launch_bounds__(256) void dequant_kernel(const uint32_t* __restrict__ qw,
                                                      const uint32_t* __restrict__ qz,
                                                      const float* __restrict__ sc,
                                                      bf16* __restrict__ out,
                                                      int J, int Kout) {
  __shared__ __align__(16) bf16 T[64 * 256];
  const int tid = threadIdx.x;
  const int tx = tid & 63, ty = tid >> 6;
  const int j0 = blockIdx.x * 64, r0 = blockIdx.y * 32;
  const int j = j0 + tx;
  const int J8 = J >> 3;
#pragma unroll
  for (int i = 0; i < 8; ++i) {
    const int r = r0 + ty * 8 + i;
    const int g = r >> 4;
    const uint32_t w = qw[(size_t)r * J + j];
    const float s = sc[(size_t)g * J + j];
    const uint32_t zb = (qz[(size_t)g * J8 + (j >> 3)] >> ((j & 7) * 4)) & 15u;
    const float zoff = (float)(zb + 1u);
    bf16x8 v;
#pragma unroll
    for (int e = 0; e < 8; ++e) {
      const float wv = (float)((w >> (e * 4)) & 15u);
      v[e] = (bf16)(s * (wv - zoff));
    }
    const int lb = (tx * 512 + (ty * 8 + i) * 16) ^ ((tx & 31) << 4);
    *(bf16x8*)((char*)T + lb) = v;
  }
  __syncthreads();
#pragma unroll
  for (int u = 0; u < 8; ++u) {
    const int unit = u * 256 + tid;
    const int jj = unit >> 5;
    const int ob = (unit & 31) * 16;
    const int lb = (jj * 512 + ob) ^ ((jj & 31) << 4);
    bf16x8 v = *(const bf16x8*)((const char*)T + lb);
    *(bf16x8*)(out + (size_t)(j0 + jj) * Kout + r0 * 8 + (ob >> 1)) = v;
  }
}

// ============================================================================
//  GEMM1 (fused 4-bit dequant): H = silu(x@Wg)*(x@Wu)
//  A = x [8192][4096] f16; B = qw_gu [512][22016] u32 (packed 4-bit, k-nibbles)
//  LDS: A dbuf 2x32KB @0, B-packed dbuf 2x8320 @65536, spak 4x2KB @82176.
// ============================================================================
#define OFF_BP 65536
#define OFF_SPK 82176

#define BAR __builtin_amdgcn_s_barrier()
#define LGKM0                                              \
  do {                                                     \
    asm volatile("s_waitcnt lgkmcnt(0)" ::: "memory");     \
    __builtin_amdgcn_sched_barrier(0);                     \
  } while (0)
#define VM2 asm volatile("s_waitcnt vmcnt(2)" ::: "memory")

#define STG_A(buf, h, tt)                                                     \
  do {                                                                        \
    gload16(sA[h][0] + (size_t)(tt) * 128,                                    \
            lds + (buf) * 32768 + (h) * 16384 + w * 1024);                    \
    gload16(sA[h][1] + (size_t)(tt) * 128,                                    \
            lds + (buf) * 32768 + (h) * 16384 + 8192 + w * 1024);             \
  } while (0)

#define STG_B(buf, tt)                                                        \
  gload16(bsrc + (size_t)(8 * (tt) + w) * WROW,                               \
          lds + OFF_BP + (buf) * 8320 + w * 1040)

#define STG_SPK(gt)                                                           \
  gload4(spakg + ((size_t)(gt) * WROW + n0) * 2 + tid,                        \
         lds + OFF_SPK + ((gt) & 3) * 2048 + w * 256)

#define MFMA_Q(MH, NH)                                                         \
  do {                                                                         \
    __builtin_amdgcn_s_setprio(1);                                             \
    _Pragma("unroll") for (int mi = 0; mi < 4; ++mi) {                         \
      _Pragma("unroll") for (int nj = 0; nj < 2; ++nj) {                       \
        acc[(MH)*4 + mi][(NH)*2 + nj] = __builtin_amdgcn_mfma_f32_16x16x32_f16( \
            av[mi][0], bv[nj][0], acc[(MH)*4 + mi][(NH)*2 + nj], 0, 0, 0);     \
        acc[(MH)*4 + mi][(NH)*2 + nj] = __builtin_amdgcn_mfma_f32_16x16x32_f16( \
            av[mi][1], bv[nj][1], acc[(MH)*4 + mi][(NH)*2 + nj], 0, 0, 0);     \
      }                                                                        \
    }                                                                          \
    __builtin_amdgcn_s_setprio(0);                                             \
    __builtin_amdgcn_sched_barrier(0);                                         \
  } while (0)

// nibble pair -> f16 weights: (0x6400|n) is exactly 1024+n; subtract exact
// (1025+z); multiply by s. All exact except the final pk_mul rounding.
__device__ __forceinline__ f16x8 unpack8(uint32_t u, f16x2 s2, f16x2 k2) {
  const uint32_t M = 0x64006400u;
  uint32_t q0 = (u & 0xFu)         | ((u << 12) & 0xF0000u) | M;
  uint32_t q1 = ((u >> 8) & 0xFu)  | ((u << 4)  & 0xF0000u) | M;
  uint32_t q2 = ((u >> 16) & 0xFu) | ((u >> 4)  & 0xF0000u) | M;
  uint32_t q3 = ((u >> 24) & 0xFu) | ((u >> 12) & 0xF0000u) | M;
  f16x2 w0 = (__builtin_bit_cast(f16x2, q0) - k2) * s2;
  f16x2 w1 = (__builtin_bit_cast(f16x2, q1) - k2) * s2;
  f16x2 w2 = (__builtin_bit_cast(f16x2, q2) - k2) * s2;
  f16x2 w3 = (__builtin_bit_cast(f16x2, q3) - k2) * s2;
  f16x8 r;
  r[0] = w0[0]; r[1] = w0[1]; r[2] = w1[0]; r[3] = w1[1];
  r[4] = w2[0]; r[5] = w2[1]; r[6] = w3[0]; r[7] = w3[1];
  return r;
}

__global__ __launch_bounds__(512, 2) void gemm1q(const f16* __restrict__ A,
                                                 const uint32_t* __restrict__ qw,
                                                 const uint32_t* __restrict__ spakg,
                                                 bf16* __restrict__ H) {
  extern __shared__ char lds[];
  const int tid = threadIdx.x;
  const int lane = tid & 63, w = tid >> 6;
  const int wr = w >> 2, wc = w & 3;
  const int fr = lane & 15, fg = lane >> 4;
  constexpr int NT = HIDDEN / 64;  // 64 K-tiles, 32 groups

  const int wg = blockIdx.x;
  const int nb = wg % (WROW / 256), mb = wg / (WROW / 256);
  const int m0 = mb << 8, n0 = nb << 8;

  // ---- A stage source pointers (linear LDS dest d -> row r, swizzled col cL)
  const char* sA[2][2];
#pragma unroll
  for (int h = 0; h < 2; ++h)
#pragma unroll
    for (int l = 0; l < 2; ++l) {
      const int d = h * 16384 + (l * 512 + tid) * 16;
      const int r = d >> 7;
      const int cL = (d & 127) ^ ((r & 7) << 4);
      sA[h][l] = (const char*)A + (size_t)(m0 + r) * (size_t)(HIDDEN * 2) + cL;
    }
  // ---- B stage source: lane's 4-n chunk -> qw col (interleaved gate/up map)
  const int n4 = n0 + lane * 4;
  const int grp4 = n4 >> 5, win4 = n4 & 31;
  const int jg4 = (win4 < 16) ? grp4 * 16 + win4 : INTER + grp4 * 16 + (win4 - 16);
  const uint32_t* bsrc = qw + jg4;

  // ---- fragment read offsets
  const int swz = (fr & 7) << 4;
  const int ck[2] = {(fg * 16) ^ swz, (64 + fg * 16) ^ swz};
  const int aro = (wr * 64 + fr) * 128;
  auto lda = [&](int buf, int mh, int mi, int kk) -> f16x8 {
    return *(const f16x8*)(lds + buf * 32768 + mh * 16384 + aro + mi * 2048 + ck[kk]);
  };
  const int ncol[2][2] = {{wc * 32 + fr, wc * 32 + 16 + fr},
                          {wc * 32 + 128 + fr, wc * 32 + 144 + fr}};  // [nh][nj]

  f32x4 acc[8][4];
#pragma unroll
  for (int i = 0; i < 8; ++i)
#pragma unroll
    for (int j = 0; j < 4; ++j) acc[i][j] = (f32x4)0.0f;
  f16x8 av[4][2], bv[2][2];
  f16x2 s2r[2][2], k2r[2][2];  // [nh][nj], refreshed every even tile

  // ---- prologue: A(0) both halves, B(0), spak g0/g1, A1(1) last (stays in flight)
  STG_A(0, 0, 0);
  STG_A(0, 1, 0);
  STG_B(0, 0);
  STG_SPK(0);
  STG_SPK(1);
  STG_A(1, 1, 1);
  VM2;  // everything except A1(1) landed
  BAR;

  for (int t = 0; t < NT; ++t) {
    const int cb = t & 1, nx = cb ^ 1, g = t >> 1;
    const int t1 = (t + 1 < NT) ? t + 1 : 0;
    const int t2 = (t + 2 < NT) ? t + 2 : 0;

    // ---- ph1: read A-h0 + B-nh0(+spak), stage A0(t+1), B(t+1); MFMA Q(0,0)
#pragma unroll
    for (int mi = 0; mi < 4; ++mi) { av[mi][0] = lda(cb, 0, mi, 0); av[mi][1] = lda(cb, 0, mi, 1); }
    uint32_t bu[2][2];
#pragma unroll
    for (int nj = 0; nj < 2; ++nj)
#pragma unroll
      for (int kk = 0; kk < 2; ++kk)
        bu[nj][kk] = *(const uint32_t*)(lds + OFF_BP + cb * 8320 + (kk * 4 + fg) * 1040 +
                                        ncol[0][nj] * 4);
    if ((t & 1) == 0) {
      const char* sp = lds + OFF_SPK + (g & 3) * 2048;
#pragma unroll
      for (int nh = 0; nh < 2; ++nh)
#pragma unroll
        for (int nj = 0; nj < 2; ++nj) {
          s2r[nh][nj] = *(const f16x2*)(sp + ncol[nh][nj] * 8);
          k2r[nh][nj] = *(const f16x2*)(sp + ncol[nh][nj] * 8 + 4);
        }
    }
    STG_A(nx, 0, t1);
    STG_B(nx, t1);
    BAR; LGKM0;
#pragma unroll
    for (int nj = 0; nj < 2; ++nj)
#pragma unroll
      for (int kk = 0; kk < 2; ++kk)
        bv[nj][kk] = unpack8(bu[nj][kk], s2r[0][nj], k2r[0][nj]);
    MFMA_Q(0, 0);
    BAR;

    // ---- ph2: read A-h1; MFMA Q(1,0)
#pragma unroll
    for (int mi = 0; mi < 4; ++mi) { av[mi][0] = lda(cb, 1, mi, 0); av[mi][1] = lda(cb, 1, mi, 1); }
    BAR; LGKM0;
    MFMA_Q(1, 0);
    BAR;

    // ---- ph3: read B-nh1, stage A1(t+2); MFMA Q(1,1)
#pragma unroll
    for (int nj = 0; nj < 2; ++nj)
#pragma unroll
      for (int kk = 0; kk < 2; ++kk)
        bu[nj][kk] = *(const uint32_t*)(lds + OFF_BP + cb * 8320 + (kk * 4 + fg) * 1040 +
                                        ncol[1][nj] * 4);
    STG_A(cb, 1, t2);
    BAR; LGKM0;
#pragma unroll
    for (int nj = 0; nj < 2; ++nj)
#pragma unroll
      for (int kk = 0; kk < 2; ++kk)
        bv[nj][kk] = unpack8(bu[nj][kk], s2r[1][nj], k2r[1][nj]);
    MFMA_Q(1, 1);
    BAR;

    // ---- ph4: re-read A-h0; VM2; (even t) stage spak g+2; MFMA Q(0,1)
#pragma unroll
    for (int mi = 0; mi < 4; ++mi) { av[mi][0] = lda(cb, 0, mi, 0); av[mi][1] = lda(cb, 0, mi, 1); }
    VM2;
    if ((t & 1) == 0) {
      const int gt = (g + 2 < 32) ? g + 2 : 31;
      STG_SPK(gt);
    }
    BAR; LGKM0;
    MFMA_Q(0, 1);
    BAR;
  }
  asm volatile("s_waitcnt vmcnt(0)" ::: "memory");

  // ---- epilogue: h = silu(g)*u -> bf16
#pragma unroll
  for (int mh = 0; mh < 2; ++mh)
#pragma unroll
    for (int mi = 0; mi < 4; ++mi)
#pragma unroll
      for (int nh = 0; nh < 2; ++nh) {
        const f32x4 gv4 = acc[mh * 4 + mi][nh * 2];
        const f32x4 uv4 = acc[mh * 4 + mi][nh * 2 + 1];
        const int col = (n0 >> 1) + wc * 16 + nh * 64 + fr;
#pragma unroll
        for (int rr = 0; rr < 4; ++rr) {
          const int row = m0 + wr * 64 + mh * 128 + mi * 16 + fg * 4 + rr;
          const float gv = gv4[rr], uv = uv4[rr];
          H[(size_t)row * INTER + col] = (bf16)(gv / (1.0f + __expf(-gv)) * uv);
        }
      }
}

// ---------------- GEMM2: 256x256 8-phase bf16 (unchanged, working) ----------
#define OFF_A2 0
#define OFF_B2 32768

#define STG2(mat, buf, h, t)                                                   \
  do {                                                                         \
    gload16(s##mat[h][0] + (size_t)(t) * 128,                                  \
            lds + (buf) * 65536 + OFF_##mat + (h) * 16384 + w * 1024);         \
    gload16(s##mat[h][1] + (size_t)(t) * 128,                                  \
            lds + (buf) * 65536 + OFF_##mat + (h) * 16384 + 8192 + w * 1024);  \
  } while (0)
#define VM6 asm volatile("s_waitcnt vmcnt(6)" ::: "memory")

#define MFMA_Q2(MH, NH)                                                        \
  do {                                                                         \
    __builtin_amdgcn_s_setprio(1);                                             \
    _Pragma("unroll") for (int mi = 0; mi < 4; ++mi) {                         \
      _Pragma("unroll") for (int nj = 0; nj < 2; ++nj) {                       \
        acc[(MH)*4 + mi][(NH)*2 + nj] = __builtin_amdgcn_mfma_f32_16x16x32_bf16( \
            av[mi][0], bv[nj][0], acc[(MH)*4 + mi][(NH)*2 + nj], 0, 0, 0);     \
        acc[(MH)*4 + mi][(NH)*2 + nj] = __builtin_amdgcn_mfma_f32_16x16x32_bf16( \
            av[mi][1], bv[nj][1], acc[(MH)*4 + mi][(NH)*2 + nj], 0, 0, 0);     \
      }                                                                        \
    }                                                                          \
    __builtin_amdgcn_s_setprio(0);                                             \
    __builtin_amdgcn_sched_barrier(0);                                         \
  } while (0)

template <int K, int NT, int NNB>
__global__ __launch_bounds__(512, 2) void gemm8p(const bf16* __restrict__ A,
                                                 const bf16* __restrict__ Bm,
                                                 float* __restrict__ O) {
  extern __shared__ char lds[];
  const int tid = threadIdx.x;
  const int lane = tid & 63, w = tid >> 6;
  const int wr = w >> 2, wc = w & 3;
  const int fr = lane & 15, fg = lane >> 4;

  const int wg = blockIdx.x;
  const int nb = wg % NNB, mb = wg / NNB;
  const int m0 = mb << 8, n0 = nb << 8;

  const char* sA2[2][2];
  const char* sB2[2][2];
#pragma unroll
  for (int h = 0; h < 2; ++h)
#pragma unroll
    for (int l = 0; l < 2; ++l) {
      const int d = h * 16384 + (l * 512 + tid) * 16;
      const int r = d >> 7;
      const int cL = (d & 127) ^ ((r & 7) << 4);
      sA2[h][l] = (const char*)A + (size_t)(m0 + r) * (size_t)(K * 2) + cL;
      sB2[h][l] = (const char*)Bm + (size_t)(n0 + r) * (size_t)(K * 2) + cL;
    }

  const int swz = (fr & 7) << 4;
  const int ck[2] = {(fg * 16) ^ swz, (64 + fg * 16) ^ swz};
  const int aro = (wr * 64 + fr) * 128;
  const int bro = OFF_B2 + (wc * 32 + fr) * 128;

  auto lda = [&](int buf, int mh, int mi, int kk) -> bf16x8 {
    return *(const bf16x8*)(lds + buf * 65536 + mh * 16384 + aro + mi * 2048 + ck[kk]);
  };
  auto ldb = [&](int buf, int nh, int nj, int kk) -> bf16x8 {
    return *(const bf16x8*)(lds + buf * 65536 + bro + nh * 16384 + nj * 2048 + ck[kk]);
  };

  f32x4 acc[8][4];
#pragma unroll
  for (int i = 0; i < 8; ++i)
#pragma unroll
    for (int j = 0; j < 4; ++j) acc[i][j] = (f32x4)0.0f;
  bf16x8 av[4][2], bv[2][2];

  STG2(A2, 0, 0, 0);
  STG2(B2, 0, 0, 0);
  STG2(B2, 0, 1, 0);
  STG2(A2, 0, 1, 0);
  STG2(A2, 1, 0, 1);
  STG2(B2, 1, 1, 1);
  STG2(A2, 1, 1, 1);
  VM6;
  BAR;

  for (int t = 0; t < NT; ++t) {
    const int cb = t & 1, nx = cb ^ 1;
    const int t1 = (t + 1 < NT) ? t + 1 : 0;
    const int t2 = (t + 2 < NT) ? t + 2 : 0;

#pragma unroll
    for (int mi = 0; mi < 4; ++mi) { av[mi][0] = lda(cb, 0, mi, 0); av[mi][1] = lda(cb, 0, mi, 1); }
#pragma unroll
    for (int nj = 0; nj < 2; ++nj) { bv[nj][0] = ldb(cb, 0, nj, 0); bv[nj][1] = ldb(cb, 0, nj, 1); }
    STG2(B2, nx, 0, t1);
    BAR; LGKM0;
    MFMA_Q2(0, 0);
    BAR;

#pragma unroll
    for (int nj = 0; nj < 2; ++nj) { bv[nj][0] = ldb(cb, 1, nj, 0); bv[nj][1] = ldb(cb, 1, nj, 1); }
    STG2(A2, cb, 0, t2);
    BAR; LGKM0;
    MFMA_Q2(0, 1);
    BAR;

#pragma unroll
    for (int mi = 0; mi < 4; ++mi) { av[mi][0] = lda(cb, 1, mi, 0); av[mi][1] = lda(cb, 1, mi, 1); }
    STG2(B2, cb, 1, t2);
    BAR; LGKM0;
    MFMA_Q2(1, 1);
    BAR;

#pragma unroll
    for (int nj = 0; nj < 2; ++nj) { bv[nj][0] = ldb(cb, 0, nj, 0); bv[nj][1] = ldb(cb, 0, nj, 1); }
    STG2(A2, cb, 1, t2);
    VM6;
    BAR; LGKM0;
    MFMA_Q2(1, 0);
    BAR;
  }

#pragma unroll
  for (int mh = 0; mh < 2; ++mh)
#pragma unroll
    for (int mi = 0; mi < 4; ++mi)
#pragma unroll
      for (int nh = 0; nh < 2; ++nh)
#pragma unroll
        for (int nj = 0; nj < 2; ++nj) {
          const f32x4 a = acc[mh * 4 + mi][nh * 2 + nj];
          const int col = n0 + wc * 32 + nh * 128 + nj * 16 + fr;
#pragma unroll
          for (int rr = 0; rr < 4; ++rr) {
            const int row = m0 + wr * 64 + mh * 128 + mi * 16 + fg * 4 + rr;
            __builtin_nontemporal_store(a[rr], &O[(size_t)row * HIDDEN + col]);
          }
        }
}

extern "C" void kernel_launch(void* const* d_in, const int* in_sizes, int n_in,
                              void* d_out, int out_size, void* d_ws, size_t ws_size,
                              hipStream_t stream) {
  (void)in_sizes; (void)n_in; (void)out_size; (void)ws_size;
  const float*    x     = (const float*)d_in[0];
  const uint32_t* qw_gu = (const uint32_t*)d_in[1];
  const uint32_t* qz_gu = (const uint32_t*)d_in[2];
  const float*    sc_gu = (const float*)d_in[3];
  const uint32_t* qw_d  = (const uint32_t*)d_in[5];
  const uint32_t* qz_d  = (const uint32_t*)d_in[6];
  const float*    sc_d  = (const float*)d_in[7];
  float*          out   = (float*)d_out;

  char* ws = (char*)d_ws;
  const size_t XB  = (size_t)NTOK * HIDDEN * 2;    // 64 MiB (x f16)
  const size_t W2B = (size_t)HIDDEN * INTER * 2;   // 86 MiB (W2^T bf16)
  const size_t HB  = (size_t)NTOK * INTER * 2;     // 172 MiB (h bf16)
  f16*      xb    = (f16*)ws;
  bf16*     wt    = (bf16*)(ws + XB);
  bf16*     hb    = (bf16*)(ws + XB + W2B);
  uint32_t* spakg = (uint32_t*)(ws + XB + W2B + HB);

  hipFuncSetAttribute((const void*)&gemm1q,
                      hipFuncAttributeMaxDynamicSharedMemorySize, 90368);
  hipFuncSetAttribute((const void*)&gemm8p<INTER, INTER / 64, HIDDEN / 256>,
                      hipFuncAttributeMaxDynamicSharedMemorySize, 131072);

  cvt_f16_kernel<<<NTOK * HIDDEN / 2048, 256, 0, stream>>>(x, xb);
  spak_kernel<<<32 * WROW / 256, 256, 0, stream>>>(qz_gu, sc_gu, spakg);

  gemm1q<<<(WROW / 256) * (NTOK / 256), 512, 90368, stream>>>(xb, qw_gu, spakg, hb);

  dequant_kernel<<<dim3(HIDDEN / 64, (INTER / 8) / 32), 256, 0, stream>>>(
      qw_d, qz_d, sc_d, wt, HIDDEN, INTER);
  gemm8p<INTER, INTER / 64, HIDDEN / 256>
      <<<(HIDDEN / 256) * (NTOK / 256), 512, 131072, stream>>>(hb, wt, out);
}

// Round 8
// 2125.187 us; speedup vs baseline: 1.0794x; 1.0794x over previous
//
#include <hip/hip_runtime.h>
#include <stdint.h>

#define HIDDEN 4096
#define INTER  11008
#define NTOK   8192   // B*S = 4*2048
#define WROW   22016  // 2*INTER, qw_gu row length in u32

typedef __bf16 bf16;
typedef __bf16 bf16x8 __attribute__((ext_vector_type(8)));
typedef _Float16 f16;
typedef _Float16 f16x2 __attribute__((ext_vector_type(2)));
typedef _Float16 f16x8 __attribute__((ext_vector_type(8)));
typedef float  f32x4  __attribute__((ext_vector_type(4)));

__device__ __forceinline__ void gload16(const void* g, void* l) {
  __builtin_amdgcn_global_load_lds(
      (const __attribute__((address_space(1))) void*)g,
      (__attribute__((address_space(3))) void*)l, 16, 0, 0);
}
__device__ __forceinline__ void gload4(const void* g, void* l) {
  __builtin_amdgcn_global_load_lds(
      (const __attribute__((address_space(1))) void*)g,
      (__attribute__((address_space(3))) void*)l, 4, 0, 0);
}

// ---------------- x: f32 -> f16, k-axis sigma-permuted within each 8 --------
// out order per 8-block: [x0,x4,x1,x5,x2,x6,x3,x7]  (matches cheap B unpack)
__global__ __launch_bounds__(256) void cvt_f16_kernel(const float* __restrict__ x,
                                                      f16* __restrict__ y) {
  const int i = (blockIdx.x * 256 + threadIdx.x) * 8;
  f32x4 a = *(const f32x4*)(x + i);
  f32x4 b = *(const f32x4*)(x + i + 4);
  f16x8 v;
#pragma unroll
  for (int j = 0; j < 4; ++j) { v[2 * j] = (f16)a[j]; v[2 * j + 1] = (f16)b[j]; }
  *(f16x8*)(y + i) = v;
}

// ---------------- spak: per (group, interleaved-col) (s2, k2) f16x2 pairs ----
// layout: u32 spak[(g*22016 + n)*2 + {0: (s,s), 1: (1025+z, 1025+z)}]
__global__ __launch_bounds__(256) void spak_kernel(const uint32_t* __restrict__ qz,
                                                   const float* __restrict__ sc,
                                                   uint32_t* __restrict__ outp) {
  const int idx = blockIdx.x * 256 + threadIdx.x;  // g*22016 + n
  const int gq = idx / WROW;
  const int n = idx - gq * WROW;
  const int grp = n >> 5, win = n & 31;
  const int jg = (win < 16) ? grp * 16 + win : INTER + grp * 16 + (win - 16);
  const float s = sc[(size_t)gq * WROW + jg];
  const uint32_t z = (qz[(size_t)gq * (WROW / 8) + (jg >> 3)] >> ((jg & 7) * 4)) & 15u;
  union { f16 h[2]; uint32_t u; } a, b;
  a.h[0] = (f16)s; a.h[1] = (f16)s;
  b.h[0] = (f16)(float)(1025u + z); b.h[1] = b.h[0];
  outp[(size_t)idx * 2 + 0] = a.u;
  outp[(size_t)idx * 2 + 1] = b.u;
}

// ---------------- GPTQ dequant (W2) -> W^T [J][Kout] bf16 (unchanged) -------
__global__ __launch_bounds__(256) void dequant_kernel(const uint32_t* __restrict__ qw,
                                                      const uint32_t* __restrict__ qz,
                                                      const float* __restrict__ sc,
                                                      bf16* __restrict__ out,
                                                      int J, int Kout) {
  __shared__ __align__(16) bf16 T[64 * 256];
  const int tid = threadIdx.x;
  const int tx = tid & 63, ty = tid >> 6;
  const int j0 = blockIdx.x * 64, r0 = blockIdx.y * 32;
  const int j = j0 + tx;
  const int J8 = J >> 3;
#pragma unroll
  for (int i = 0; i < 8; ++i) {
    const int r = r0 + ty * 8 + i;
    const int g = r >> 4;
    const uint32_t w = qw[(size_t)r * J + j];
    const float s = sc[(size_t)g * J + j];
    const uint32_t zb = (qz[(size_t)g * J8 + (j >> 3)] >> ((j & 7) * 4)) & 15u;
    const float zoff = (float)(zb + 1u);
    bf16x8 v;
#pragma unroll
    for (int e = 0; e < 8; ++e) {
      const float wv = (float)((w >> (e * 4)) & 15u);
      v[e] = (bf16)(s * (wv - zoff));
    }
    const int lb = (tx * 512 + (ty * 8 + i) * 16) ^ ((tx & 31) << 4);
    *(bf16x8*)((char*)T + lb) = v;
  }
  __syncthreads();
#pragma unroll
  for (int u = 0; u < 8; ++u) {
    const int unit = u * 256 + tid;
    const int jj = unit >> 5;
    const int ob = (unit & 31) * 16;
    const int lb = (jj * 512 + ob) ^ ((jj & 31) << 4);
    bf16x8 v = *(const bf16x8*)((const char*)T + lb);
    *(bf16x8*)(out + (size_t)(j0 + jj) * Kout + r0 * 8 + (ob >> 1)) = v;
  }
}

// ============================================================================
//  GEMM1 (fused 4-bit dequant, 3-phase): H = silu(x@Wg)*(x@Wu)
//  A = xb [8192][4096] f16 (sigma-permuted k); B = qw_gu u32 packed.
//  LDS: A dbuf 2x32KB @0, B-packed dbuf 2x8320 @65536, spak 4x2KB @82176.
//  Per tile: ph1 Q(0,0) | ph2 Q(1,0) | ph3 Q(1,1)+Q(0,1). All staging -> nx.
// ============================================================================
#define OFF_BP 65536
#define OFF_SPK 82176

#define BAR __builtin_amdgcn_s_barrier()
#define LGKM0                                              \
  do {                                                     \
    asm volatile("s_waitcnt lgkmcnt(0)" ::: "memory");     \
    __builtin_amdgcn_sched_barrier(0);                     \
  } while (0)
#define VM2 asm volatile("s_waitcnt vmcnt(2)" ::: "memory")
#define VM3 asm volatile("s_waitcnt vmcnt(3)" ::: "memory")

#define STG_A(buf, h, tt)                                                      \
  do {                                                                         \
    gload16(sA00 + ((size_t)((h) * 128) * (HIDDEN * 2)) + (size_t)(tt) * 128,  \
            lds + (buf) * 32768 + (h) * 16384 + w * 1024);                     \
    gload16(sA00 + ((size_t)((h) * 128 + 64) * (HIDDEN * 2)) + (size_t)(tt) * 128, \
            lds + (buf) * 32768 + (h) * 16384 + 8192 + w * 1024);              \
  } while (0)

#define STG_B(buf, tt)                                                        \
  gload16(bsrc + (size_t)(8 * (tt) + w) * WROW,                               \
          lds + OFF_BP + (buf) * 8320 + w * 1040)

#define STG_SPK(gt)                                                           \
  gload4(spakg + ((size_t)(gt) * WROW + n0) * 2 + tid,                        \
         lds + OFF_SPK + ((gt) & 3) * 2048 + w * 256)

// sigma unpack: pairs (n0,n4),(n1,n5),(n2,n6),(n3,n7); exact until final mul
__device__ __forceinline__ f16x8 unpack8s(uint32_t u, f16x2 s2, f16x2 k2) {
  const uint32_t MSK = 0x000F000Fu, M = 0x64006400u;
  uint32_t q0 = (u & MSK) | M;
  uint32_t q1 = ((u >> 4) & MSK) | M;
  uint32_t q2 = ((u >> 8) & MSK) | M;
  uint32_t q3 = ((u >> 12) & MSK) | M;
  f16x2 w0 = (__builtin_bit_cast(f16x2, q0) - k2) * s2;
  f16x2 w1 = (__builtin_bit_cast(f16x2, q1) - k2) * s2;
  f16x2 w2 = (__builtin_bit_cast(f16x2, q2) - k2) * s2;
  f16x2 w3 = (__builtin_bit_cast(f16x2, q3) - k2) * s2;
  f16x8 r;
  r[0] = w0[0]; r[1] = w0[1]; r[2] = w1[0]; r[3] = w1[1];
  r[4] = w2[0]; r[5] = w2[1]; r[6] = w3[0]; r[7] = w3[1];
  return r;
}

// unpack one B fragment then its 4 independent MFMAs (interleaves VALU/MFMA)
#define UNP_SL(AVH, BUIDX, NH, NJ, KK, R, C)                                   \
  do {                                                                         \
    bv[NJ][KK] = unpack8s(bu[BUIDX], s2r[NH][NJ], k2r[NH][NJ]);                \
    _Pragma("unroll") for (int mi = 0; mi < 4; ++mi)                           \
      acc[(R) + mi][C] = __builtin_amdgcn_mfma_f32_16x16x32_f16(               \
          AVH[mi][KK], bv[NJ][KK], acc[(R) + mi][C], 0, 0, 0);                 \
  } while (0)

// 16 MFMAs, kk-outer (no dependent back-to-back pairs)
#define MFMA16(AVH, R, CBASE)                                                  \
  do {                                                                         \
    _Pragma("unroll") for (int kk = 0; kk < 2; ++kk)                           \
      _Pragma("unroll") for (int nj = 0; nj < 2; ++nj)                         \
        _Pragma("unroll") for (int mi = 0; mi < 4; ++mi)                       \
          acc[(R) + mi][(CBASE) + nj] = __builtin_amdgcn_mfma_f32_16x16x32_f16(\
              AVH[mi][kk], bv[nj][kk], acc[(R) + mi][(CBASE) + nj], 0, 0, 0);  \
  } while (0)

__global__ __launch_bounds__(512, 2) void gemm1q(const f16* __restrict__ A,
                                                 const uint32_t* __restrict__ qw,
                                                 const uint32_t* __restrict__ spakg,
                                                 bf16* __restrict__ H) {
  extern __shared__ char lds[];
  const int tid = threadIdx.x;
  const int lane = tid & 63, w = tid >> 6;
  const int wr = w >> 2, wc = w & 3;
  const int fr = lane & 15, fg = lane >> 4;
  constexpr int NT = HIDDEN / 64;  // 64 K-tiles, 32 groups

  const int wg = blockIdx.x;
  const int nb = wg % (WROW / 256), mb = wg / (WROW / 256);
  const int m0 = mb << 8, n0 = nb << 8;

  // ---- single A stage base (other 3 ptrs are compile-time offsets)
  const int rbase = tid >> 3;                 // 0..63
  const int cbyte0 = (tid & 7) * 16;
  const int cL0 = cbyte0 ^ ((rbase & 7) << 4);
  const char* sA00 = (const char*)A + (size_t)(m0 + rbase) * (size_t)(HIDDEN * 2) + cL0;

  // ---- B stage source: lane's 4-n chunk -> qw col (interleaved gate/up map)
  const int n4 = n0 + lane * 4;
  const int grp4 = n4 >> 5, win4 = n4 & 31;
  const int jg4 = (win4 < 16) ? grp4 * 16 + win4 : INTER + grp4 * 16 + (win4 - 16);
  const uint32_t* bsrc = qw + jg4;

  // ---- fragment read offsets
  const int swz = (fr & 7) << 4;
  const int ck[2] = {(fg * 16) ^ swz, (64 + fg * 16) ^ swz};
  const int aro = (wr * 64 + fr) * 128;
  auto lda = [&](int buf, int mh, int mi, int kk) -> f16x8 {
    return *(const f16x8*)(lds + buf * 32768 + mh * 16384 + aro + mi * 2048 + ck[kk]);
  };
  const int ncol[2][2] = {{wc * 32 + fr, wc * 32 + 16 + fr},
                          {wc * 32 + 128 + fr, wc * 32 + 144 + fr}};  // [nh][nj]

  f32x4 acc[8][4];
#pragma unroll
  for (int i = 0; i < 8; ++i)
#pragma unroll
    for (int j = 0; j < 4; ++j) acc[i][j] = (f32x4)0.0f;
  f16x8 av0[4][2], av1[4][2], bv[2][2];
  uint32_t bu[8];
  f16x2 s2r[2][2], k2r[2][2];

  // ---- prologue: queue [spk0, A0,A0, B, A1,A1]; drain first 4
  STG_SPK(0);
  STG_A(0, 0, 0);
  STG_B(0, 0);
  STG_A(0, 1, 0);
  VM2;
  BAR;

  for (int t = 0; t < NT; ++t) {
    const int cb = t & 1, nx = cb ^ 1, g = t >> 1;
    const int t1 = (t + 1 < NT) ? t + 1 : 0;  // dummy keeps vmcnt exact

    // ======== ph1: read A-h0 + all 8 B words (+spak); stage A0,B -> nx;
    //          Q(0,0) with interleaved unpack ========
#pragma unroll
    for (int mi = 0; mi < 4; ++mi) { av0[mi][0] = lda(cb, 0, mi, 0); av0[mi][1] = lda(cb, 0, mi, 1); }
#pragma unroll
    for (int nh = 0; nh < 2; ++nh)
#pragma unroll
      for (int nj = 0; nj < 2; ++nj)
#pragma unroll
        for (int kk = 0; kk < 2; ++kk)
          bu[nh * 4 + nj * 2 + kk] = *(const uint32_t*)(
              lds + OFF_BP + cb * 8320 + (kk * 4 + fg) * 1040 + ncol[nh][nj] * 4);
    if ((t & 1) == 0) {
      const char* sp = lds + OFF_SPK + (g & 3) * 2048;
#pragma unroll
      for (int nh = 0; nh < 2; ++nh)
#pragma unroll
        for (int nj = 0; nj < 2; ++nj) {
          s2r[nh][nj] = *(const f16x2*)(sp + ncol[nh][nj] * 8);
          k2r[nh][nj] = *(const f16x2*)(sp + ncol[nh][nj] * 8 + 4);
        }
    }
    STG_A(nx, 0, t1);
    STG_B(nx, t1);
    VM3;   // drains prev A1 pair (this tile's ph2 input)
    BAR; LGKM0;
    __builtin_amdgcn_s_setprio(1);
    UNP_SL(av0, 0, 0, 0, 0, 0, 0);
    UNP_SL(av0, 1, 0, 0, 1, 0, 0);
    UNP_SL(av0, 2, 0, 1, 0, 0, 1);
    UNP_SL(av0, 3, 0, 1, 1, 0, 1);
    __builtin_amdgcn_s_setprio(0);
    __builtin_amdgcn_sched_barrier(0);
    BAR;

    // ======== ph2: read A-h1; stage (spak?,) A1 -> nx; Q(1,0) ========
#pragma unroll
    for (int mi = 0; mi < 4; ++mi) { av1[mi][0] = lda(cb, 1, mi, 0); av1[mi][1] = lda(cb, 1, mi, 1); }
    if (t & 1) {
      const int gt = (g + 1 < 32) ? g + 1 : 31;
      STG_SPK(gt);   // FIRST in ph2 queue so ph3's VM2 drains it
    }
    STG_A(nx, 1, t1);
    BAR; LGKM0;
    __builtin_amdgcn_s_setprio(1);
    MFMA16(av1, 4, 0);
    __builtin_amdgcn_s_setprio(0);
    __builtin_amdgcn_sched_barrier(0);
    BAR;

    // ======== ph3 (merged): Q(1,1) interleaved-unpack + Q(0,1) ========
    __builtin_amdgcn_s_setprio(1);
    UNP_SL(av1, 4, 1, 0, 0, 4, 2);
    UNP_SL(av1, 5, 1, 0, 1, 4, 2);
    UNP_SL(av1, 6, 1, 1, 0, 4, 3);
    UNP_SL(av1, 7, 1, 1, 1, 4, 3);
    MFMA16(av0, 0, 2);
    __builtin_amdgcn_s_setprio(0);
    __builtin_amdgcn_sched_barrier(0);
    VM2;   // drains A0,B(,spk) for next ph1; leaves next A1 pair in flight
    BAR;
  }
  asm volatile("s_waitcnt vmcnt(0)" ::: "memory");

  // ---- epilogue: h = silu(g)*u -> bf16
#pragma unroll
  for (int mh = 0; mh < 2; ++mh)
#pragma unroll
    for (int mi = 0; mi < 4; ++mi)
#pragma unroll
      for (int nh = 0; nh < 2; ++nh) {
        const f32x4 gv4 = acc[mh * 4 + mi][nh * 2];
        const f32x4 uv4 = acc[mh * 4 + mi][nh * 2 + 1];
        const int col = (n0 >> 1) + wc * 16 + nh * 64 + fr;
#pragma unroll
        for (int rr = 0; rr < 4; ++rr) {
          const int row = m0 + wr * 64 + mh * 128 + mi * 16 + fg * 4 + rr;
          const float gv = gv4[rr], uv = uv4[rr];
          H[(size_t)row * INTER + col] = (bf16)(gv / (1.0f + __expf(-gv)) * uv);
        }
      }
}

// ---------------- GEMM2: 256x256 8-phase bf16 (unchanged, working) ----------
#define OFF_A2 0
#define OFF_B2 32768

#define STG2(mat, buf, h, t)                                                   \
  do {                                                                         \
    gload16(s##mat[h][0] + (size_t)(t) * 128,                                  \
            lds + (buf) * 65536 + OFF_##mat + (h) * 16384 + w * 1024);         \
    gload16(s##mat[h][1] + (size_t)(t) * 128,                                  \
            lds + (buf) * 65536 + OFF_##mat + (h) * 16384 + 8192 + w * 1024);  \
  } while (0)
#define VM6 asm volatile("s_waitcnt vmcnt(6)" ::: "memory")

#define MFMA_Q2(MH, NH)                                                        \
  do {                                                                         \
    __builtin_amdgcn_s_setprio(1);                                             \
    _Pragma("unroll") for (int kk = 0; kk < 2; ++kk) {                         \
      _Pragma("unroll") for (int nj = 0; nj < 2; ++nj) {                       \
        _Pragma("unroll") for (int mi = 0; mi < 4; ++mi) {                     \
          acc[(MH)*4 + mi][(NH)*2 + nj] = __builtin_amdgcn_mfma_f32_16x16x32_bf16( \
              av[mi][kk], bv[nj][kk], acc[(MH)*4 + mi][(NH)*2 + nj], 0, 0, 0); \
        }                                                                      \
      }                                                                        \
    }                                                                          \
    __builtin_amdgcn_s_setprio(0);                                             \
    __builtin_amdgcn_sched_barrier(0);                                         \
  } while (0)

template <int K, int NT, int NNB>
__global__ __launch_bounds__(512, 2) void gemm8p(const bf16* __restrict__ A,
                                                 const bf16* __restrict__ Bm,
                                                 float* __restrict__ O) {
  extern __shared__ char lds[];
  const int tid = threadIdx.x;
  const int lane = tid & 63, w = tid >> 6;
  const int wr = w >> 2, wc = w & 3;
  const int fr = lane & 15, fg = lane >> 4;

  const int wg = blockIdx.x;
  const int nb = wg % NNB, mb = wg / NNB;
  const int m0 = mb << 8, n0 = nb << 8;

  const char* sA2[2][2];
  const char* sB2[2][2];
#pragma unroll
  for (int h = 0; h < 2; ++h)
#pragma unroll
    for (int l = 0; l < 2; ++l) {
      const int d = h * 16384 + (l * 512 + tid) * 16;
      const int r = d >> 7;
      const int cL = (d & 127) ^ ((r & 7) << 4);
      sA2[h][l] = (const char*)A + (size_t)(m0 + r) * (size_t)(K * 2) + cL;
      sB2[h][l] = (const char*)Bm + (size_t)(n0 + r) * (size_t)(K * 2) + cL;
    }

  const int swz = (fr & 7) << 4;
  const int ck[2] = {(fg * 16) ^ swz, (64 + fg * 16) ^ swz};
  const int aro = (wr * 64 + fr) * 128;
  const int bro = OFF_B2 + (wc * 32 + fr) * 128;

  auto lda = [&](int buf, int mh, int mi, int kk) -> bf16x8 {
    return *(const bf16x8*)(lds + buf * 65536 + mh * 16384 + aro + mi * 2048 + ck[kk]);
  };
  auto ldb = [&](int buf, int nh, int nj, int kk) -> bf16x8 {
    return *(const bf16x8*)(lds + buf * 65536 + bro + nh * 16384 + nj * 2048 + ck[kk]);
  };

  f32x4 acc[8][4];
#pragma unroll
  for (int i = 0; i < 8; ++i)
#pragma unroll
    for (int j = 0; j < 4; ++j) acc[i][j] = (f32x4)0.0f;
  bf16x8 av[4][2], bv[2][2];

  STG2(A2, 0, 0, 0);
  STG2(B2, 0, 0, 0);
  STG2(B2, 0, 1, 0);
  STG2(A2, 0, 1, 0);
  STG2(A2, 1, 0, 1);
  STG2(B2, 1, 1, 1);
  STG2(A2, 1, 1, 1);
  VM6;
  BAR;

  for (int t = 0; t < NT; ++t) {
    const int cb = t & 1, nx = cb ^ 1;
    const int t1 = (t + 1 < NT) ? t + 1 : 0;
    const int t2 = (t + 2 < NT) ? t + 2 : 0;

#pragma unroll
    for (int mi = 0; mi < 4; ++mi) { av[mi][0] = lda(cb, 0, mi, 0); av[mi][1] = lda(cb, 0, mi, 1); }
#pragma unroll
    for (int nj = 0; nj < 2; ++nj) { bv[nj][0] = ldb(cb, 0, nj, 0); bv[nj][1] = ldb(cb, 0, nj, 1); }
    STG2(B2, nx, 0, t1);
    BAR; LGKM0;
    MFMA_Q2(0, 0);
    BAR;

#pragma unroll
    for (int nj = 0; nj < 2; ++nj) { bv[nj][0] = ldb(cb, 1, nj, 0); bv[nj][1] = ldb(cb, 1, nj, 1); }
    STG2(A2, cb, 0, t2);
    BAR; LGKM0;
    MFMA_Q2(0, 1);
    BAR;

#pragma unroll
    for (int mi = 0; mi < 4; ++mi) { av[mi][0] = lda(cb, 1, mi, 0); av[mi][1] = lda(cb, 1, mi, 1); }
    STG2(B2, cb, 1, t2);
    BAR; LGKM0;
    MFMA_Q2(1, 1);
    BAR;

#pragma unroll
    for (int nj = 0; nj < 2; ++nj) { bv[nj][0] = ldb(cb, 0, nj, 0); bv[nj][1] = ldb(cb, 0, nj, 1); }
    STG2(A2, cb, 1, t2);
    VM6;
    BAR; LGKM0;
    MFMA_Q2(1, 0);
    BAR;
  }

#pragma unroll
  for (int mh = 0; mh < 2; ++mh)
#pragma unroll
    for (int mi = 0; mi < 4; ++mi)
#pragma unroll
      for (int nh = 0; nh < 2; ++nh)
#pragma unroll
        for (int nj = 0; nj < 2; ++nj) {
          const f32x4 a = acc[mh * 4 + mi][nh * 2 + nj];
          const int col = n0 + wc * 32 + nh * 128 + nj * 16 + fr;
#pragma unroll
          for (int rr = 0; rr < 4; ++rr) {
            const int row = m0 + wr * 64 + mh * 128 + mi * 16 + fg * 4 + rr;
            __builtin_nontemporal_store(a[rr], &O[(size_t)row * HIDDEN + col]);
          }
        }
}

extern "C" void kernel_launch(void* const* d_in, const int* in_sizes, int n_in,
                              void* d_out, int out_size, void* d_ws, size_t ws_size,
                              hipStream_t stream) {
  (void)in_sizes; (void)n_in; (void)out_size; (void)ws_size;
  const float*    x     = (const float*)d_in[0];
  const uint32_t* qw_gu = (const uint32_t*)d_in[1];
  const uint32_t* qz_gu = (const uint32_t*)d_in[2];
  const float*    sc_gu = (const float*)d_in[3];
  const uint32_t* qw_d  = (const uint32_t*)d_in[5];
  const uint32_t* qz_d  = (const uint32_t*)d_in[6];
  const float*    sc_d  = (const float*)d_in[7];
  float*          out   = (float*)d_out;

  char* ws = (char*)d_ws;
  const size_t XB  = (size_t)NTOK * HIDDEN * 2;    // 64 MiB (x f16, permuted)
  const size_t W2B = (size_t)HIDDEN * INTER * 2;   // 86 MiB (W2^T bf16)
  const size_t HB  = (size_t)NTOK * INTER * 2;     // 172 MiB (h bf16)
  f16*      xb    = (f16*)ws;
  bf16*     wt    = (bf16*)(ws + XB);
  bf16*     hb    = (bf16*)(ws + XB + W2B);
  uint32_t* spakg = (uint32_t*)(ws + XB + W2B + HB);

  hipFuncSetAttribute((const void*)&gemm1q,
                      hipFuncAttributeMaxDynamicSharedMemorySize, 90368);
  hipFuncSetAttribute((const void*)&gemm8p<INTER, INTER / 64, HIDDEN / 256>,
                      hipFuncAttributeMaxDynamicSharedMemorySize, 131072);

  cvt_f16_kernel<<<NTOK * HIDDEN / 2048, 256, 0, stream>>>(x, xb);
  spak_kernel<<<32 * WROW / 256, 256, 0, stream>>>(qz_gu, sc_gu, spakg);

  gemm1q<<<(WROW / 256) * (NTOK / 256), 512, 90368, stream>>>(xb, qw_gu, spakg, hb);

  dequant_kernel<<<dim3(HIDDEN / 64, (INTER / 8) / 32), 256, 0, stream>>>(
      qw_d, qz_d, sc_d, wt, HIDDEN, INTER);
  gemm8p<INTER, INTER / 64, HIDDEN / 256>
      <<<(HIDDEN / 256) * (NTOK / 256), 512, 131072, stream>>>(hb, wt, out);
}

// Round 10
// 2112.896 us; speedup vs baseline: 1.0857x; 1.0058x over previous
//
#include <hip/hip_runtime.h>
#include <stdint.h>

#define HIDDEN 4096
#define INTER  11008
#define NTOK   8192   // B*S = 4*2048
#define WROW   22016  // 2*INTER, qw_gu row length in u32

typedef __bf16 bf16;
typedef __bf16 bf16x8 __attribute__((ext_vector_type(8)));
typedef _Float16 f16;
typedef _Float16 f16x2 __attribute__((ext_vector_type(2)));
typedef _Float16 f16x8 __attribute__((ext_vector_type(8)));
typedef float  f32x4  __attribute__((ext_vector_type(4)));
typedef unsigned int u32x4 __attribute__((ext_vector_type(4)));

__device__ __forceinline__ void gload16(const void* g, void* l) {
  __builtin_amdgcn_global_load_lds(
      (const __attribute__((address_space(1))) void*)g,
      (__attribute__((address_space(3))) void*)l, 16, 0, 0);
}
__device__ __forceinline__ void gload4(const void* g, void* l) {
  __builtin_amdgcn_global_load_lds(
      (const __attribute__((address_space(1))) void*)g,
      (__attribute__((address_space(3))) void*)l, 4, 0, 0);
}

// ---------------- x: f32 -> f16, k-axis sigma-permuted within each 8 --------
// out order per 8-block: [x0,x4,x1,x5,x2,x6,x3,x7]  (matches cheap B unpack)
__global__ __launch_bounds__(256) void cvt_f16_kernel(const float* __restrict__ x,
                                                      f16* __restrict__ y) {
  const int i = (blockIdx.x * 256 + threadIdx.x) * 8;
  f32x4 a = *(const f32x4*)(x + i);
  f32x4 b = *(const f32x4*)(x + i + 4);
  f16x8 v;
#pragma unroll
  for (int j = 0; j < 4; ++j) { v[2 * j] = (f16)a[j]; v[2 * j + 1] = (f16)b[j]; }
  *(f16x8*)(y + i) = v;
}

// ---------------- spak: per (group, interleaved-col) (s2, k2) f16x2 pairs ----
// layout: u32 spak[(g*22016 + n)*2 + {0: (s,s), 1: (1025+z, 1025+z)}]
__global__ __launch_bounds__(256) void spak_kernel(const uint32_t* __restrict__ qz,
                                                   const float* __restrict__ sc,
                                                   uint32_t* __restrict__ outp) {
  const int idx = blockIdx.x * 256 + threadIdx.x;  // g*22016 + n
  const int gq = idx / WROW;
  const int n = idx - gq * WROW;
  const int grp = n >> 5, win = n & 31;
  const int jg = (win < 16) ? grp * 16 + win : INTER + grp * 16 + (win - 16);
  const float s = sc[(size_t)gq * WROW + jg];
  const uint32_t z = (qz[(size_t)gq * (WROW / 8) + (jg >> 3)] >> ((jg & 7) * 4)) & 15u;
  union { f16 h[2]; uint32_t u; } a, b;
  a.h[0] = (f16)s; a.h[1] = (f16)s;
  b.h[0] = (f16)(float)(1025u + z); b.h[1] = b.h[0];
  outp[(size_t)idx * 2 + 0] = a.u;
  outp[(size_t)idx * 2 + 1] = b.u;
}

// ---------------- B repack: qw_gu -> reader-friendly per (nb, kt) blocks ----
// out[nb][kt][c], c=0..2047 u32. chunk=c>>2 = (r*4+wc)*16+fr; word j=c&3:
// col = wc*32 + fr + (j&1)*16 + (j>>1)*128; row = kt*8+r; col->jg interleave.
__global__ __launch_bounds__(256) void repackB_kernel(const uint32_t* __restrict__ qw,
                                                      uint32_t* __restrict__ outp) {
  const size_t idx = (size_t)blockIdx.x * 256 + threadIdx.x;
  const int c = (int)(idx & 2047);
  const int kt = (int)((idx >> 11) & 63);
  const int nb = (int)(idx >> 17);
  const int j = c & 3;
  const int chunk = c >> 2;
  const int r = chunk >> 6;
  const int wc = (chunk >> 4) & 3;
  const int fr = chunk & 15;
  const int col = wc * 32 + fr + (j & 1) * 16 + (j >> 1) * 128;
  const int n = nb * 256 + col;
  const int grp = n >> 5, win = n & 31;
  const int jg = (win < 16) ? grp * 16 + win : INTER + grp * 16 + (win - 16);
  outp[idx] = qw[(size_t)(kt * 8 + r) * WROW + jg];
}

// ---------------- GPTQ dequant (W2) -> W^T [J][Kout] bf16 (unchanged) -------
__global__ __launch_bounds__(256) void dequant_kernel(const uint32_t* __restrict__ qw,
                                                      const uint32_t* __restrict__ qz,
                                                      const float* __restrict__ sc,
                                                      bf16* __restrict__ out,
                                                      int J, int Kout) {
  __shared__ __align__(16) bf16 T[64 * 256];
  const int tid = threadIdx.x;
  const int tx = tid & 63, ty = tid >> 6;
  const int j0 = blockIdx.x * 64, r0 = blockIdx.y * 32;
  const int j = j0 + tx;
  const int J8 = J >> 3;
#pragma unroll
  for (int i = 0; i < 8; ++i) {
    const int r = r0 + ty * 8 + i;
    const int g = r >> 4;
    const uint32_t w = qw[(size_t)r * J + j];
    const float s = sc[(size_t)g * J + j];
    const uint32_t zb = (qz[(size_t)g * J8 + (j >> 3)] >> ((j & 7) * 4)) & 15u;
    const float zoff = (float)(zb + 1u);
    bf16x8 v;
#pragma unroll
    for (int e = 0; e < 8; ++e) {
      const float wv = (float)((w >> (e * 4)) & 15u);
      v[e] = (bf16)(s * (wv - zoff));
    }
    const int lb = (tx * 512 + (ty * 8 + i) * 16) ^ ((tx & 31) << 4);
    *(bf16x8*)((char*)T + lb) = v;
  }
  __syncthreads();
#pragma unroll
  for (int u = 0; u < 8; ++u) {
    const int unit = u * 256 + tid;
    const int jj = unit >> 5;
    const int ob = (unit & 31) * 16;
    const int lb = (jj * 512 + ob) ^ ((jj & 31) << 4);
    bf16x8 v = *(const bf16x8*)((const char*)T + lb);
    *(bf16x8*)(out + (size_t)(j0 + jj) * Kout + r0 * 8 + (ob >> 1)) = v;
  }
}

// ============================================================================
//  GEMM1 (fused 4-bit dequant, 3-phase): H = silu(x@Wg)*(x@Wu)
//  A = xb [8192][4096] f16 (sigma-permuted k); B = repacked qw (linear blocks).
//  LDS: A dbuf 2x32KB @0, B dbuf 2x8KB @65536, spak 4x2KB @81920. 88 KiB.
//  Phase/barrier/vmcnt structure IDENTICAL to the verified R8-bench kernel;
//  only the B source (repack) and B LDS reads (2x b128 vs 8x b32) changed.
// ============================================================================
#define OFF_BP 65536
#define OFF_SPK 81920

#define BAR __builtin_amdgcn_s_barrier()
#define LGKM0                                              \
  do {                                                     \
    asm volatile("s_waitcnt lgkmcnt(0)" ::: "memory");     \
    __builtin_amdgcn_sched_barrier(0);                     \
  } while (0)
#define VM2 asm volatile("s_waitcnt vmcnt(2)" ::: "memory")
#define VM3 asm volatile("s_waitcnt vmcnt(3)" ::: "memory")

#define STG_A(buf, h, tt)                                                      \
  do {                                                                         \
    gload16(sA00 + ((size_t)((h) * 128) * (HIDDEN * 2)) + (size_t)(tt) * 128,  \
            lds + (buf) * 32768 + (h) * 16384 + w * 1024);                     \
    gload16(sA00 + ((size_t)((h) * 128 + 64) * (HIDDEN * 2)) + (size_t)(tt) * 128, \
            lds + (buf) * 32768 + (h) * 16384 + 8192 + w * 1024);              \
  } while (0)

#define STG_B(buf, tt)                                                         \
  gload16(repk_src + (size_t)(tt) * 2048 + tid * 4,                            \
          lds + OFF_BP + (buf) * 8192 + tid * 16)

#define STG_SPK(gt)                                                           \
  gload4(spakg + ((size_t)(gt) * WROW + n0) * 2 + tid,                        \
         lds + OFF_SPK + ((gt) & 3) * 2048 + w * 256)

// sigma unpack: pairs (n0,n4),(n1,n5),(n2,n6),(n3,n7); exact until final mul
__device__ __forceinline__ f16x8 unpack8s(uint32_t u, f16x2 s2, f16x2 k2) {
  const uint32_t MSK = 0x000F000Fu, M = 0x64006400u;
  uint32_t q0 = (u & MSK) | M;
  uint32_t q1 = ((u >> 4) & MSK) | M;
  uint32_t q2 = ((u >> 8) & MSK) | M;
  uint32_t q3 = ((u >> 12) & MSK) | M;
  f16x2 w0 = (__builtin_bit_cast(f16x2, q0) - k2) * s2;
  f16x2 w1 = (__builtin_bit_cast(f16x2, q1) - k2) * s2;
  f16x2 w2 = (__builtin_bit_cast(f16x2, q2) - k2) * s2;
  f16x2 w3 = (__builtin_bit_cast(f16x2, q3) - k2) * s2;
  f16x8 r;
  r[0] = w0[0]; r[1] = w0[1]; r[2] = w1[0]; r[3] = w1[1];
  r[4] = w2[0]; r[5] = w2[1]; r[6] = w3[0]; r[7] = w3[1];
  return r;
}

// unpack one B fragment then its 4 independent MFMAs (interleaves VALU/MFMA)
#define UNP_SL(AVH, BUIDX, NH, NJ, KK, R, C)                                   \
  do {                                                                         \
    bv[NJ][KK] = unpack8s(bu[BUIDX], s2r[NH][NJ], k2r[NH][NJ]);                \
    _Pragma("unroll") for (int mi = 0; mi < 4; ++mi)                           \
      acc[(R) + mi][C] = __builtin_amdgcn_mfma_f32_16x16x32_f16(               \
          AVH[mi][KK], bv[NJ][KK], acc[(R) + mi][C], 0, 0, 0);                 \
  } while (0)

// 16 MFMAs, kk-outer (no dependent back-to-back pairs)
#define MFMA16(AVH, R, CBASE)                                                  \
  do {                                                                         \
    _Pragma("unroll") for (int kk = 0; kk < 2; ++kk)                           \
      _Pragma("unroll") for (int nj = 0; nj < 2; ++nj)                         \
        _Pragma("unroll") for (int mi = 0; mi < 4; ++mi)                       \
          acc[(R) + mi][(CBASE) + nj] = __builtin_amdgcn_mfma_f32_16x16x32_f16(\
              AVH[mi][kk], bv[nj][kk], acc[(R) + mi][(CBASE) + nj], 0, 0, 0);  \
  } while (0)

__global__ __launch_bounds__(512, 2) void gemm1q(const f16* __restrict__ A,
                                                 const uint32_t* __restrict__ repk,
                                                 const uint32_t* __restrict__ spakg,
                                                 bf16* __restrict__ H) {
  extern __shared__ char lds[];
  const int tid = threadIdx.x;
  const int lane = tid & 63, w = tid >> 6;
  const int wr = w >> 2, wc = w & 3;
  const int fr = lane & 15, fg = lane >> 4;
  constexpr int NT = HIDDEN / 64;  // 64 K-tiles, 32 groups

  const int wg = blockIdx.x;
  const int nb = wg % (WROW / 256), mb = wg / (WROW / 256);
  const int m0 = mb << 8, n0 = nb << 8;

  // ---- single A stage base (other 3 ptrs are compile-time offsets)
  const int rbase = tid >> 3;                 // 0..63
  const int cbyte0 = (tid & 7) * 16;
  const int cL0 = cbyte0 ^ ((rbase & 7) << 4);
  const char* sA00 = (const char*)A + (size_t)(m0 + rbase) * (size_t)(HIDDEN * 2) + cL0;

  // ---- B stage source: linear repacked block for this nb
  const uint32_t* repk_src = repk + (size_t)nb * 64 * 2048;

  // ---- fragment read offsets
  const int swz = (fr & 7) << 4;
  const int ck[2] = {(fg * 16) ^ swz, (64 + fg * 16) ^ swz};
  const int aro = (wr * 64 + fr) * 128;
  auto lda = [&](int buf, int mh, int mi, int kk) -> f16x8 {
    return *(const f16x8*)(lds + buf * 32768 + mh * 16384 + aro + mi * 2048 + ck[kk]);
  };
  const int c1b = ((fg * 4 + wc) * 16 + fr) * 16;  // b128 chunk (r=fg, kk=0)
  const int ncol[2][2] = {{wc * 32 + fr, wc * 32 + 16 + fr},
                          {wc * 32 + 128 + fr, wc * 32 + 144 + fr}};  // [nh][nj]

  f32x4 acc[8][4];
#pragma unroll
  for (int i = 0; i < 8; ++i)
#pragma unroll
    for (int j = 0; j < 4; ++j) acc[i][j] = (f32x4)0.0f;
  f16x8 av0[4][2], av1[4][2], bv[2][2];
  uint32_t bu[8];
  f16x2 s2r[2][2], k2r[2][2];  // [nh][nj], refreshed every even tile

  // ---- prologue: queue [spk0, A0,A0, B, A1,A1]; drain first 4
  STG_SPK(0);
  STG_A(0, 0, 0);
  STG_B(0, 0);
  STG_A(0, 1, 0);
  VM2;
  BAR;

  for (int t = 0; t < NT; ++t) {
    const int cb = t & 1, nx = cb ^ 1, g = t >> 1;
    const int t1 = (t + 1 < NT) ? t + 1 : 0;  // dummy keeps vmcnt exact

    // ======== ph1: read A-h0 + all 8 B words via 2x b128 (+spak);
    //          stage A0,B -> nx; Q(0,0) with interleaved unpack ========
#pragma unroll
    for (int mi = 0; mi < 4; ++mi) { av0[mi][0] = lda(cb, 0, mi, 0); av0[mi][1] = lda(cb, 0, mi, 1); }
    {
      u32x4 v1 = *(const u32x4*)(lds + OFF_BP + cb * 8192 + c1b);
      u32x4 v2 = *(const u32x4*)(lds + OFF_BP + cb * 8192 + c1b + 4096);
      bu[0] = v1.x; bu[1] = v2.x; bu[2] = v1.y; bu[3] = v2.y;
      bu[4] = v1.z; bu[5] = v2.z; bu[6] = v1.w; bu[7] = v2.w;
    }
    if ((t & 1) == 0) {
      const char* sp = lds + OFF_SPK + (g & 3) * 2048;
#pragma unroll
      for (int nh = 0; nh < 2; ++nh)
#pragma unroll
        for (int nj = 0; nj < 2; ++nj) {
          s2r[nh][nj] = *(const f16x2*)(sp + ncol[nh][nj] * 8);
          k2r[nh][nj] = *(const f16x2*)(sp + ncol[nh][nj] * 8 + 4);
        }
    }
    STG_A(nx, 0, t1);
    STG_B(nx, t1);
    VM3;   // drains prev A1 pair (this tile's ph2 input)
    BAR; LGKM0;
    __builtin_amdgcn_s_setprio(1);
    UNP_SL(av0, 0, 0, 0, 0, 0, 0);
    UNP_SL(av0, 1, 0, 0, 1, 0, 0);
    UNP_SL(av0, 2, 0, 1, 0, 0, 1);
    UNP_SL(av0, 3, 0, 1, 1, 0, 1);
    __builtin_amdgcn_s_setprio(0);
    __builtin_amdgcn_sched_barrier(0);
    BAR;

    // ======== ph2: read A-h1; stage (spak?,) A1 -> nx; Q(1,0) ========
#pragma unroll
    for (int mi = 0; mi < 4; ++mi) { av1[mi][0] = lda(cb, 1, mi, 0); av1[mi][1] = lda(cb, 1, mi, 1); }
    if (t & 1) {
      const int gt = (g + 1 < 32) ? g + 1 : 31;
      STG_SPK(gt);   // FIRST in ph2 queue so ph3's VM2 drains it
    }
    STG_A(nx, 1, t1);
    BAR; LGKM0;
    __builtin_amdgcn_s_setprio(1);
    MFMA16(av1, 4, 0);
    __builtin_amdgcn_s_setprio(0);
    __builtin_amdgcn_sched_barrier(0);
    BAR;

    // ======== ph3 (merged): Q(1,1) interleaved-unpack + Q(0,1) ========
    __builtin_amdgcn_s_setprio(1);
    UNP_SL(av1, 4, 1, 0, 0, 4, 2);
    UNP_SL(av1, 5, 1, 0, 1, 4, 2);
    UNP_SL(av1, 6, 1, 1, 0, 4, 3);
    UNP_SL(av1, 7, 1, 1, 1, 4, 3);
    MFMA16(av0, 0, 2);
    __builtin_amdgcn_s_setprio(0);
    __builtin_amdgcn_sched_barrier(0);
    VM2;   // drains A0,B(,spk) for next ph1; leaves next A1 pair in flight
    BAR;
  }
  asm volatile("s_waitcnt vmcnt(0)" ::: "memory");

  // ---- epilogue: h = silu(g)*u -> bf16
#pragma unroll
  for (int mh = 0; mh < 2; ++mh)
#pragma unroll
    for (int mi = 0; mi < 4; ++mi)
#pragma unroll
      for (int nh = 0; nh < 2; ++nh) {
        const f32x4 gv4 = acc[mh * 4 + mi][nh * 2];
        const f32x4 uv4 = acc[mh * 4 + mi][nh * 2 + 1];
        const int col = (n0 >> 1) + wc * 16 + nh * 64 + fr;
#pragma unroll
        for (int rr = 0; rr < 4; ++rr) {
          const int row = m0 + wr * 64 + mh * 128 + mi * 16 + fg * 4 + rr;
          const float gv = gv4[rr], uv = uv4[rr];
          H[(size_t)row * INTER + col] = (bf16)(gv / (1.0f + __expf(-gv)) * uv);
        }
      }
}

// ---------------- GEMM2: 256x256 8-phase bf16 (unchanged, working) ----------
#define OFF_A2 0
#define OFF_B2 32768

#define STG2(mat, buf, h, t)                                                   \
  do {                                                                         \
    gload16(s##mat[h][0] + (size_t)(t) * 128,                                  \
            lds + (buf) * 65536 + OFF_##mat + (h) * 16384 + w * 1024);         \
    gload16(s##mat[h][1] + (size_t)(t) * 128,                                  \
            lds + (buf) * 65536 + OFF_##mat + (h) * 16384 + 8192 + w * 1024);  \
  } while (0)
#define VM6 asm volatile("s_waitcnt vmcnt(6)" ::: "memory")

#define MFMA_Q2(MH, NH)                                                        \
  do {                                                                         \
    __builtin_amdgcn_s_setprio(1);                                             \
    _Pragma("unroll") for (int kk = 0; kk < 2; ++kk) {                         \
      _Pragma("unroll") for (int nj = 0; nj < 2; ++nj) {                       \
        _Pragma("unroll") for (int mi = 0; mi < 4; ++mi) {                     \
          acc[(MH)*4 + mi][(NH)*2 + nj] = __builtin_amdgcn_mfma_f32_16x16x32_bf16( \
              av[mi][kk], bv[nj][kk], acc[(MH)*4 + mi][(NH)*2 + nj], 0, 0, 0); \
        }                                                                      \
      }                                                                        \
    }                                                                          \
    __builtin_amdgcn_s_setprio(0);                                             \
    __builtin_amdgcn_sched_barrier(0);                                         \
  } while (0)

template <int K, int NT, int NNB>
__global__ __launch_bounds__(512, 2) void gemm8p(const bf16* __restrict__ A,
                                                 const bf16* __restrict__ Bm,
                                                 float* __restrict__ O) {
  extern __shared__ char lds[];
  const int tid = threadIdx.x;
  const int lane = tid & 63, w = tid >> 6;
  const int wr = w >> 2, wc = w & 3;
  const int fr = lane & 15, fg = lane >> 4;

  const int wg = blockIdx.x;
  const int nb = wg % NNB, mb = wg / NNB;
  const int m0 = mb << 8, n0 = nb << 8;

  const char* sA2[2][2];
  const char* sB2[2][2];
#pragma unroll
  for (int h = 0; h < 2; ++h)
#pragma unroll
    for (int l = 0; l < 2; ++l) {
      const int d = h * 16384 + (l * 512 + tid) * 16;
      const int r = d >> 7;
      const int cL = (d & 127) ^ ((r & 7) << 4);
      sA2[h][l] = (const char*)A + (size_t)(m0 + r) * (size_t)(K * 2) + cL;
      sB2[h][l] = (const char*)Bm + (size_t)(n0 + r) * (size_t)(K * 2) + cL;
    }

  const int swz = (fr & 7) << 4;
  const int ck[2] = {(fg * 16) ^ swz, (64 + fg * 16) ^ swz};
  const int aro = (wr * 64 + fr) * 128;
  const int bro = OFF_B2 + (wc * 32 + fr) * 128;

  auto lda = [&](int buf, int mh, int mi, int kk) -> bf16x8 {
    return *(const bf16x8*)(lds + buf * 65536 + mh * 16384 + aro + mi * 2048 + ck[kk]);
  };
  auto ldb = [&](int buf, int nh, int nj, int kk) -> bf16x8 {
    return *(const bf16x8*)(lds + buf * 65536 + bro + nh * 16384 + nj * 2048 + ck[kk]);
  };

  f32x4 acc[8][4];
#pragma unroll
  for (int i = 0; i < 8; ++i)
#pragma unroll
    for (int j = 0; j < 4; ++j) acc[i][j] = (f32x4)0.0f;
  bf16x8 av[4][2], bv[2][2];

  STG2(A2, 0, 0, 0);
  STG2(B2, 0, 0, 0);
  STG2(B2, 0, 1, 0);
  STG2(A2, 0, 1, 0);
  STG2(A2, 1, 0, 1);
  STG2(B2, 1, 1, 1);
  STG2(A2, 1, 1, 1);
  VM6;
  BAR;

  for (int t = 0; t < NT; ++t) {
    const int cb = t & 1, nx = cb ^ 1;
    const int t1 = (t + 1 < NT) ? t + 1 : 0;
    const int t2 = (t + 2 < NT) ? t + 2 : 0;

#pragma unroll
    for (int mi = 0; mi < 4; ++mi) { av[mi][0] = lda(cb, 0, mi, 0); av[mi][1] = lda(cb, 0, mi, 1); }
#pragma unroll
    for (int nj = 0; nj < 2; ++nj) { bv[nj][0] = ldb(cb, 0, nj, 0); bv[nj][1] = ldb(cb, 0, nj, 1); }
    STG2(B2, nx, 0, t1);
    BAR; LGKM0;
    MFMA_Q2(0, 0);
    BAR;

#pragma unroll
    for (int nj = 0; nj < 2; ++nj) { bv[nj][0] = ldb(cb, 1, nj, 0); bv[nj][1] = ldb(cb, 1, nj, 1); }
    STG2(A2, cb, 0, t2);
    BAR; LGKM0;
    MFMA_Q2(0, 1);
    BAR;

#pragma unroll
    for (int mi = 0; mi < 4; ++mi) { av[mi][0] = lda(cb, 1, mi, 0); av[mi][1] = lda(cb, 1, mi, 1); }
    STG2(B2, cb, 1, t2);
    BAR; LGKM0;
    MFMA_Q2(1, 1);
    BAR;

#pragma unroll
    for (int nj = 0; nj < 2; ++nj) { bv[nj][0] = ldb(cb, 0, nj, 0); bv[nj][1] = ldb(cb, 0, nj, 1); }
    STG2(A2, cb, 1, t2);
    VM6;
    BAR; LGKM0;
    MFMA_Q2(1, 0);
    BAR;
  }

#pragma unroll
  for (int mh = 0; mh < 2; ++mh)
#pragma unroll
    for (int mi = 0; mi < 4; ++mi)
#pragma unroll
      for (int nh = 0; nh < 2; ++nh)
#pragma unroll
        for (int nj = 0; nj < 2; ++nj) {
          const f32x4 a = acc[mh * 4 + mi][nh * 2 + nj];
          const int col = n0 + wc * 32 + nh * 128 + nj * 16 + fr;
#pragma unroll
          for (int rr = 0; rr < 4; ++rr) {
            const int row = m0 + wr * 64 + mh * 128 + mi * 16 + fg * 4 + rr;
            __builtin_nontemporal_store(a[rr], &O[(size_t)row * HIDDEN + col]);
          }
        }
}

extern "C" void kernel_launch(void* const* d_in, const int* in_sizes, int n_in,
                              void* d_out, int out_size, void* d_ws, size_t ws_size,
                              hipStream_t stream) {
  (void)in_sizes; (void)n_in; (void)out_size; (void)ws_size;
  const float*    x     = (const float*)d_in[0];
  const uint32_t* qw_gu = (const uint32_t*)d_in[1];
  const uint32_t* qz_gu = (const uint32_t*)d_in[2];
  const float*    sc_gu = (const float*)d_in[3];
  const uint32_t* qw_d  = (const uint32_t*)d_in[5];
  const uint32_t* qz_d  = (const uint32_t*)d_in[6];
  const float*    sc_d  = (const float*)d_in[7];
  float*          out   = (float*)d_out;

  char* ws = (char*)d_ws;
  const size_t XB  = (size_t)NTOK * HIDDEN * 2;        // 64 MiB (x f16)
  const size_t W2B = (size_t)HIDDEN * INTER * 2;       // 86 MiB (W2^T bf16)
  const size_t HB  = (size_t)NTOK * INTER * 2;         // 172 MiB (h bf16)
  const size_t SPB = (size_t)32 * WROW * 2 * 4;        // 5.6 MiB spak
  f16*      xb    = (f16*)ws;
  bf16*     wt    = (bf16*)(ws + XB);
  bf16*     hb    = (bf16*)(ws + XB + W2B);
  uint32_t* spakg = (uint32_t*)(ws + XB + W2B + HB);
  uint32_t* repk  = (uint32_t*)(ws + XB + W2B + HB + SPB);  // 43 MiB

  hipFuncSetAttribute((const void*)&gemm1q,
                      hipFuncAttributeMaxDynamicSharedMemorySize, 90112);
  hipFuncSetAttribute((const void*)&gemm8p<INTER, INTER / 64, HIDDEN / 256>,
                      hipFuncAttributeMaxDynamicSharedMemorySize, 131072);

  cvt_f16_kernel<<<NTOK * HIDDEN / 2048, 256, 0, stream>>>(x, xb);
  spak_kernel<<<32 * WROW / 256, 256, 0, stream>>>(qz_gu, sc_gu, spakg);
  repackB_kernel<<<((WROW / 256) * 64 * 2048) / 256, 256, 0, stream>>>(qw_gu, repk);

  gemm1q<<<(WROW / 256) * (NTOK / 256), 512, 90112, stream>>>(xb, repk, spakg, hb);

  dequant_kernel<<<dim3(HIDDEN / 64, (INTER / 8) / 32), 256, 0, stream>>>(
      qw_d, qz_d, sc_d, wt, HIDDEN, INTER);
  gemm8p<INTER, INTER / 64, HIDDEN / 256>
      <<<(HIDDEN / 256) * (NTOK / 256), 512, 131072, stream>>>(hb, wt, out);
}

// Round 11
// 2084.586 us; speedup vs baseline: 1.1004x; 1.0136x over previous
//
#include <hip/hip_runtime.h>
#include <stdint.h>

#define HIDDEN 4096
#define INTER  11008
#define NTOK   8192   // B*S = 4*2048
#define WROW   22016  // 2*INTER, qw_gu row length in u32

typedef __bf16 bf16;
typedef __bf16 bf16x8 __attribute__((ext_vector_type(8)));
typedef _Float16 f16;
typedef _Float16 f16x2 __attribute__((ext_vector_type(2)));
typedef _Float16 f16x8 __attribute__((ext_vector_type(8)));
typedef float  f32x4  __attribute__((ext_vector_type(4)));
typedef unsigned int u32x4 __attribute__((ext_vector_type(4)));

__device__ __forceinline__ void gload16(const void* g, void* l) {
  __builtin_amdgcn_global_load_lds(
      (const __attribute__((address_space(1))) void*)g,
      (__attribute__((address_space(3))) void*)l, 16, 0, 0);
}
__device__ __forceinline__ void gload4(const void* g, void* l) {
  __builtin_amdgcn_global_load_lds(
      (const __attribute__((address_space(1))) void*)g,
      (__attribute__((address_space(3))) void*)l, 4, 0, 0);
}

// ---------------- x: f32 -> f16, k-axis sigma-permuted within each 8 --------
// out order per 8-block: [x0,x4,x1,x5,x2,x6,x3,x7]  (matches cheap B unpack)
__global__ __launch_bounds__(256) void cvt_f16_kernel(const float* __restrict__ x,
                                                      f16* __restrict__ y) {
  const int i = (blockIdx.x * 256 + threadIdx.x) * 8;
  f32x4 a = *(const f32x4*)(x + i);
  f32x4 b = *(const f32x4*)(x + i + 4);
  f16x8 v;
#pragma unroll
  for (int j = 0; j < 4; ++j) { v[2 * j] = (f16)a[j]; v[2 * j + 1] = (f16)b[j]; }
  *(f16x8*)(y + i) = v;
}

// ---------------- spak: per (group, interleaved-col) (s2, k2) f16x2 pairs ----
// layout: u32 spak[(g*22016 + n)*2 + {0: (s,s), 1: (1025+z, 1025+z)}]
__global__ __launch_bounds__(256) void spak_kernel(const uint32_t* __restrict__ qz,
                                                   const float* __restrict__ sc,
                                                   uint32_t* __restrict__ outp) {
  const int idx = blockIdx.x * 256 + threadIdx.x;  // g*22016 + n
  const int gq = idx / WROW;
  const int n = idx - gq * WROW;
  const int grp = n >> 5, win = n & 31;
  const int jg = (win < 16) ? grp * 16 + win : INTER + grp * 16 + (win - 16);
  const float s = sc[(size_t)gq * WROW + jg];
  const uint32_t z = (qz[(size_t)gq * (WROW / 8) + (jg >> 3)] >> ((jg & 7) * 4)) & 15u;
  union { f16 h[2]; uint32_t u; } a, b;
  a.h[0] = (f16)s; a.h[1] = (f16)s;
  b.h[0] = (f16)(float)(1025u + z); b.h[1] = b.h[0];
  outp[(size_t)idx * 2 + 0] = a.u;
  outp[(size_t)idx * 2 + 1] = b.u;
}

// ---------------- B repack: qw_gu -> reader-friendly per (nb, kt) blocks ----
// out[nb][kt][c], c=0..2047 u32. chunk=c>>2 = (r*4+wc)*16+fr; word j=c&3:
// col = wc*32 + fr + (j&1)*16 + (j>>1)*128; row = kt*8+r; col->jg interleave.
__global__ __launch_bounds__(256) void repackB_kernel(const uint32_t* __restrict__ qw,
                                                      uint32_t* __restrict__ outp) {
  const size_t idx = (size_t)blockIdx.x * 256 + threadIdx.x;
  const int c = (int)(idx & 2047);
  const int kt = (int)((idx >> 11) & 63);
  const int nb = (int)(idx >> 17);
  const int j = c & 3;
  const int chunk = c >> 2;
  const int r = chunk >> 6;
  const int wc = (chunk >> 4) & 3;
  const int fr = chunk & 15;
  const int col = wc * 32 + fr + (j & 1) * 16 + (j >> 1) * 128;
  const int n = nb * 256 + col;
  const int grp = n >> 5, win = n & 31;
  const int jg = (win < 16) ? grp * 16 + win : INTER + grp * 16 + (win - 16);
  outp[idx] = qw[(size_t)(kt * 8 + r) * WROW + jg];
}

// ---------------- GPTQ dequant (W2) -> W^T [J][Kout] bf16 (unchanged) -------
__global__ __launch_bounds__(256) void dequant_kernel(const uint32_t* __restrict__ qw,
                                                      const uint32_t* __restrict__ qz,
                                                      const float* __restrict__ sc,
                                                      bf16* __restrict__ out,
                                                      int J, int Kout) {
  __shared__ __align__(16) bf16 T[64 * 256];
  const int tid = threadIdx.x;
  const int tx = tid & 63, ty = tid >> 6;
  const int j0 = blockIdx.x * 64, r0 = blockIdx.y * 32;
  const int j = j0 + tx;
  const int J8 = J >> 3;
#pragma unroll
  for (int i = 0; i < 8; ++i) {
    const int r = r0 + ty * 8 + i;
    const int g = r >> 4;
    const uint32_t w = qw[(size_t)r * J + j];
    const float s = sc[(size_t)g * J + j];
    const uint32_t zb = (qz[(size_t)g * J8 + (j >> 3)] >> ((j & 7) * 4)) & 15u;
    const float zoff = (float)(zb + 1u);
    bf16x8 v;
#pragma unroll
    for (int e = 0; e < 8; ++e) {
      const float wv = (float)((w >> (e * 4)) & 15u);
      v[e] = (bf16)(s * (wv - zoff));
    }
    const int lb = (tx * 512 + (ty * 8 + i) * 16) ^ ((tx & 31) << 4);
    *(bf16x8*)((char*)T + lb) = v;
  }
  __syncthreads();
#pragma unroll
  for (int u = 0; u < 8; ++u) {
    const int unit = u * 256 + tid;
    const int jj = unit >> 5;
    const int ob = (unit & 31) * 16;
    const int lb = (jj * 512 + ob) ^ ((jj & 31) << 4);
    bf16x8 v = *(const bf16x8*)((const char*)T + lb);
    *(bf16x8*)(out + (size_t)(j0 + jj) * Kout + r0 * 8 + (ob >> 1)) = v;
  }
}

// ============================================================================
//  GEMM1 (fused 4-bit dequant, 2-phase): H = silu(x@Wg)*(x@Wu)
//  A = xb [8192][4096] f16 (sigma-permuted k); B = repacked qw (linear blocks).
//  LDS: A dbuf 2x32KB @0, B dbuf 2x8KB @65536, spak 4x2KB @81920. 88 KiB.
//  Per tile: ph1 = av0 work (Q(0,0)+Q(0,1), unpack all 8 B words);
//            ph2 = av1 into SAME regs, pure 32-MFMA burst (Q(1,0)+Q(1,1)).
//  vmcnt ledger identical in shape to the verified R10 kernel (VM3 in ph1,
//  VM2 at end of tile; spak staged FIRST in odd ph2) — traced both parities.
// ============================================================================
#define OFF_BP 65536
#define OFF_SPK 81920

#define BAR __builtin_amdgcn_s_barrier()
#define LGKM0                                              \
  do {                                                     \
    asm volatile("s_waitcnt lgkmcnt(0)" ::: "memory");     \
    __builtin_amdgcn_sched_barrier(0);                     \
  } while (0)
#define VM2 asm volatile("s_waitcnt vmcnt(2)" ::: "memory")
#define VM3 asm volatile("s_waitcnt vmcnt(3)" ::: "memory")

#define STG_A(buf, h, tt)                                                      \
  do {                                                                         \
    gload16(sA00 + ((size_t)((h) * 128) * (HIDDEN * 2)) + (size_t)(tt) * 128,  \
            lds + (buf) * 32768 + (h) * 16384 + w * 1024);                     \
    gload16(sA00 + ((size_t)((h) * 128 + 64) * (HIDDEN * 2)) + (size_t)(tt) * 128, \
            lds + (buf) * 32768 + (h) * 16384 + 8192 + w * 1024);              \
  } while (0)

#define STG_B(buf, tt)                                                         \
  gload16(repk_src + (size_t)(tt) * 2048 + tid * 4,                            \
          lds + OFF_BP + (buf) * 8192 + tid * 16)

#define STG_SPK(gt)                                                           \
  gload4(spakg + ((size_t)(gt) * WROW + n0) * 2 + tid,                        \
         lds + OFF_SPK + ((gt) & 3) * 2048 + w * 256)

// sigma unpack: pairs (n0,n4),(n1,n5),(n2,n6),(n3,n7); exact until final mul
__device__ __forceinline__ f16x8 unpack8s(uint32_t u, f16x2 s2, f16x2 k2) {
  const uint32_t MSK = 0x000F000Fu, M = 0x64006400u;
  uint32_t q0 = (u & MSK) | M;
  uint32_t q1 = ((u >> 4) & MSK) | M;
  uint32_t q2 = ((u >> 8) & MSK) | M;
  uint32_t q3 = ((u >> 12) & MSK) | M;
  f16x2 w0 = (__builtin_bit_cast(f16x2, q0) - k2) * s2;
  f16x2 w1 = (__builtin_bit_cast(f16x2, q1) - k2) * s2;
  f16x2 w2 = (__builtin_bit_cast(f16x2, q2) - k2) * s2;
  f16x2 w3 = (__builtin_bit_cast(f16x2, q3) - k2) * s2;
  f16x8 r;
  r[0] = w0[0]; r[1] = w0[1]; r[2] = w1[0]; r[3] = w1[1];
  r[4] = w2[0]; r[5] = w2[1]; r[6] = w3[0]; r[7] = w3[1];
  return r;
}

// unpack one B fragment into BV[NJ][KK], then its 4 independent MFMAs (rows 0..3)
#define UNP_SL(BV, WORD, NH, NJ, KK, C)                                        \
  do {                                                                         \
    BV[NJ][KK] = unpack8s(WORD, s2r[NH][NJ], k2r[NH][NJ]);                     \
    _Pragma("unroll") for (int mi = 0; mi < 4; ++mi)                           \
      acc[mi][C] = __builtin_amdgcn_mfma_f32_16x16x32_f16(                     \
          av[mi][KK], BV[NJ][KK], acc[mi][C], 0, 0, 0);                        \
  } while (0)

__global__ __launch_bounds__(512, 2) void gemm1q(const f16* __restrict__ A,
                                                 const uint32_t* __restrict__ repk,
                                                 const uint32_t* __restrict__ spakg,
                                                 bf16* __restrict__ H) {
  extern __shared__ char lds[];
  const int tid = threadIdx.x;
  const int lane = tid & 63, w = tid >> 6;
  const int wr = w >> 2, wc = w & 3;
  const int fr = lane & 15, fg = lane >> 4;
  constexpr int NT = HIDDEN / 64;  // 64 K-tiles, 32 groups

  const int wg = blockIdx.x;
  const int nb = wg % (WROW / 256), mb = wg / (WROW / 256);
  const int m0 = mb << 8, n0 = nb << 8;

  // ---- single A stage base (other 3 ptrs are compile-time offsets)
  const int rbase = tid >> 3;                 // 0..63
  const int cbyte0 = (tid & 7) * 16;
  const int cL0 = cbyte0 ^ ((rbase & 7) << 4);
  const char* sA00 = (const char*)A + (size_t)(m0 + rbase) * (size_t)(HIDDEN * 2) + cL0;

  // ---- B stage source: linear repacked block for this nb
  const uint32_t* repk_src = repk + (size_t)nb * 64 * 2048;

  // ---- fragment read offsets
  const int swz = (fr & 7) << 4;
  const int ck[2] = {(fg * 16) ^ swz, (64 + fg * 16) ^ swz};
  const int aro = (wr * 64 + fr) * 128;
  auto lda = [&](int buf, int mh, int mi, int kk) -> f16x8 {
    return *(const f16x8*)(lds + buf * 32768 + mh * 16384 + aro + mi * 2048 + ck[kk]);
  };
  const int c1b = ((fg * 4 + wc) * 16 + fr) * 16;  // b128 chunk (r=fg, kk=0)
  const int ncol[2][2] = {{wc * 32 + fr, wc * 32 + 16 + fr},
                          {wc * 32 + 128 + fr, wc * 32 + 144 + fr}};  // [nh][nj]

  f32x4 acc[8][4];
#pragma unroll
  for (int i = 0; i < 8; ++i)
#pragma unroll
    for (int j = 0; j < 4; ++j) acc[i][j] = (f32x4)0.0f;
  f16x8 av[4][2], bv[2][2], bv2[2][2];
  f16x2 s2r[2][2], k2r[2][2];  // [nh][nj], refreshed every even tile

  // ---- prologue: queue [spk0, A0,A0, B, A1,A1]; drain first 4
  STG_SPK(0);
  STG_A(0, 0, 0);
  STG_B(0, 0);
  STG_A(0, 1, 0);
  VM2;
  BAR;

  for (int t = 0; t < NT; ++t) {
    const int cb = t & 1, nx = cb ^ 1, g = t >> 1;
    const int t1 = (t + 1 < NT) ? t + 1 : 0;  // dummy keeps vmcnt exact

    // ======== ph1: ds av0 + 2x b128 B (+spak even-t); stage A0,B -> nx;
    //          unpack all 8 words; Q(0,0)+Q(0,1) (32 MFMA, rows 0..3) ========
#pragma unroll
    for (int mi = 0; mi < 4; ++mi) { av[mi][0] = lda(cb, 0, mi, 0); av[mi][1] = lda(cb, 0, mi, 1); }
    u32x4 v1 = *(const u32x4*)(lds + OFF_BP + cb * 8192 + c1b);
    u32x4 v2 = *(const u32x4*)(lds + OFF_BP + cb * 8192 + c1b + 4096);
    if ((t & 1) == 0) {
      const char* sp = lds + OFF_SPK + (g & 3) * 2048;
#pragma unroll
      for (int nh = 0; nh < 2; ++nh)
#pragma unroll
        for (int nj = 0; nj < 2; ++nj) {
          s2r[nh][nj] = *(const f16x2*)(sp + ncol[nh][nj] * 8);
          k2r[nh][nj] = *(const f16x2*)(sp + ncol[nh][nj] * 8 + 4);
        }
    }
    STG_A(nx, 0, t1);
    STG_B(nx, t1);
    VM3;   // drains prev-tile A1 pair (+spak on even t) -> ph2 inputs ready
    BAR; LGKM0;
    __builtin_amdgcn_s_setprio(1);
    UNP_SL(bv,  v1.x, 0, 0, 0, 0);
    UNP_SL(bv,  v2.x, 0, 0, 1, 0);
    UNP_SL(bv,  v1.y, 0, 1, 0, 1);
    UNP_SL(bv,  v2.y, 0, 1, 1, 1);
    UNP_SL(bv2, v1.z, 1, 0, 0, 2);
    UNP_SL(bv2, v2.z, 1, 0, 1, 2);
    UNP_SL(bv2, v1.w, 1, 1, 0, 3);
    UNP_SL(bv2, v2.w, 1, 1, 1, 3);
    __builtin_amdgcn_s_setprio(0);
    __builtin_amdgcn_sched_barrier(0);
    BAR;

    // ======== ph2: ds av1 into SAME av regs; [odd: spak first] + stage A1;
    //          pure 32-MFMA burst Q(1,0)+Q(1,1) (rows 4..7) ========
#pragma unroll
    for (int mi = 0; mi < 4; ++mi) { av[mi][0] = lda(cb, 1, mi, 0); av[mi][1] = lda(cb, 1, mi, 1); }
    if (t & 1) {
      const int gt = (g + 1 < 32) ? g + 1 : 31;
      STG_SPK(gt);   // FIRST in ph2 queue so end-of-tile VM2 drains it
    }
    STG_A(nx, 1, t1);
    BAR; LGKM0;
    __builtin_amdgcn_s_setprio(1);
#pragma unroll
    for (int kk = 0; kk < 2; ++kk)
#pragma unroll
      for (int nj = 0; nj < 2; ++nj) {
#pragma unroll
        for (int mi = 0; mi < 4; ++mi)
          acc[4 + mi][nj] = __builtin_amdgcn_mfma_f32_16x16x32_f16(
              av[mi][kk], bv[nj][kk], acc[4 + mi][nj], 0, 0, 0);
#pragma unroll
        for (int mi = 0; mi < 4; ++mi)
          acc[4 + mi][2 + nj] = __builtin_amdgcn_mfma_f32_16x16x32_f16(
              av[mi][kk], bv2[nj][kk], acc[4 + mi][2 + nj], 0, 0, 0);
      }
    __builtin_amdgcn_s_setprio(0);
    __builtin_amdgcn_sched_barrier(0);
    VM2;   // drains A0,B(,spk) for next ph1; leaves next A1 pair in flight
    BAR;
  }
  asm volatile("s_waitcnt vmcnt(0)" ::: "memory");

  // ---- epilogue: h = silu(g)*u -> bf16
#pragma unroll
  for (int mh = 0; mh < 2; ++mh)
#pragma unroll
    for (int mi = 0; mi < 4; ++mi)
#pragma unroll
      for (int nh = 0; nh < 2; ++nh) {
        const f32x4 gv4 = acc[mh * 4 + mi][nh * 2];
        const f32x4 uv4 = acc[mh * 4 + mi][nh * 2 + 1];
        const int col = (n0 >> 1) + wc * 16 + nh * 64 + fr;
#pragma unroll
        for (int rr = 0; rr < 4; ++rr) {
          const int row = m0 + wr * 64 + mh * 128 + mi * 16 + fg * 4 + rr;
          const float gv = gv4[rr], uv = uv4[rr];
          H[(size_t)row * INTER + col] = (bf16)(gv / (1.0f + __expf(-gv)) * uv);
        }
      }
}

// ---------------- GEMM2: 256x256 8-phase bf16 (unchanged, working) ----------
#define OFF_A2 0
#define OFF_B2 32768

#define STG2(mat, buf, h, t)                                                   \
  do {                                                                         \
    gload16(s##mat[h][0] + (size_t)(t) * 128,                                  \
            lds + (buf) * 65536 + OFF_##mat + (h) * 16384 + w * 1024);         \
    gload16(s##mat[h][1] + (size_t)(t) * 128,                                  \
            lds + (buf) * 65536 + OFF_##mat + (h) * 16384 + 8192 + w * 1024);  \
  } while (0)
#define VM6 asm volatile("s_waitcnt vmcnt(6)" ::: "memory")

#define MFMA_Q2(MH, NH)                                                        \
  do {                                                                         \
    __builtin_amdgcn_s_setprio(1);                                             \
    _Pragma("unroll") for (int kk = 0; kk < 2; ++kk) {                         \
      _Pragma("unroll") for (int nj = 0; nj < 2; ++nj) {                       \
        _Pragma("unroll") for (int mi = 0; mi < 4; ++mi) {                     \
          acc[(MH)*4 + mi][(NH)*2 + nj] = __builtin_amdgcn_mfma_f32_16x16x32_bf16( \
              av[mi][kk], bv[nj][kk], acc[(MH)*4 + mi][(NH)*2 + nj], 0, 0, 0); \
        }                                                                      \
      }                                                                        \
    }                                                                          \
    __builtin_amdgcn_s_setprio(0);                                             \
    __builtin_amdgcn_sched_barrier(0);                                         \
  } while (0)

template <int K, int NT, int NNB>
__global__ __launch_bounds__(512, 2) void gemm8p(const bf16* __restrict__ A,
                                                 const bf16* __restrict__ Bm,
                                                 float* __restrict__ O) {
  extern __shared__ char lds[];
  const int tid = threadIdx.x;
  const int lane = tid & 63, w = tid >> 6;
  const int wr = w >> 2, wc = w & 3;
  const int fr = lane & 15, fg = lane >> 4;

  const int wg = blockIdx.x;
  const int nb = wg % NNB, mb = wg / NNB;
  const int m0 = mb << 8, n0 = nb << 8;

  const char* sA2[2][2];
  const char* sB2[2][2];
#pragma unroll
  for (int h = 0; h < 2; ++h)
#pragma unroll
    for (int l = 0; l < 2; ++l) {
      const int d = h * 16384 + (l * 512 + tid) * 16;
      const int r = d >> 7;
      const int cL = (d & 127) ^ ((r & 7) << 4);
      sA2[h][l] = (const char*)A + (size_t)(m0 + r) * (size_t)(K * 2) + cL;
      sB2[h][l] = (const char*)Bm + (size_t)(n0 + r) * (size_t)(K * 2) + cL;
    }

  const int swz = (fr & 7) << 4;
  const int ck[2] = {(fg * 16) ^ swz, (64 + fg * 16) ^ swz};
  const int aro = (wr * 64 + fr) * 128;
  const int bro = OFF_B2 + (wc * 32 + fr) * 128;

  auto lda = [&](int buf, int mh, int mi, int kk) -> bf16x8 {
    return *(const bf16x8*)(lds + buf * 65536 + mh * 16384 + aro + mi * 2048 + ck[kk]);
  };
  auto ldb = [&](int buf, int nh, int nj, int kk) -> bf16x8 {
    return *(const bf16x8*)(lds + buf * 65536 + bro + nh * 16384 + nj * 2048 + ck[kk]);
  };

  f32x4 acc[8][4];
#pragma unroll
  for (int i = 0; i < 8; ++i)
#pragma unroll
    for (int j = 0; j < 4; ++j) acc[i][j] = (f32x4)0.0f;
  bf16x8 av[4][2], bv[2][2];

  STG2(A2, 0, 0, 0);
  STG2(B2, 0, 0, 0);
  STG2(B2, 0, 1, 0);
  STG2(A2, 0, 1, 0);
  STG2(A2, 1, 0, 1);
  STG2(B2, 1, 1, 1);
  STG2(A2, 1, 1, 1);
  VM6;
  BAR;

  for (int t = 0; t < NT; ++t) {
    const int cb = t & 1, nx = cb ^ 1;
    const int t1 = (t + 1 < NT) ? t + 1 : 0;
    const int t2 = (t + 2 < NT) ? t + 2 : 0;

#pragma unroll
    for (int mi = 0; mi < 4; ++mi) { av[mi][0] = lda(cb, 0, mi, 0); av[mi][1] = lda(cb, 0, mi, 1); }
#pragma unroll
    for (int nj = 0; nj < 2; ++nj) { bv[nj][0] = ldb(cb, 0, nj, 0); bv[nj][1] = ldb(cb, 0, nj, 1); }
    STG2(B2, nx, 0, t1);
    BAR; LGKM0;
    MFMA_Q2(0, 0);
    BAR;

#pragma unroll
    for (int nj = 0; nj < 2; ++nj) { bv[nj][0] = ldb(cb, 1, nj, 0); bv[nj][1] = ldb(cb, 1, nj, 1); }
    STG2(A2, cb, 0, t2);
    BAR; LGKM0;
    MFMA_Q2(0, 1);
    BAR;

#pragma unroll
    for (int mi = 0; mi < 4; ++mi) { av[mi][0] = lda(cb, 1, mi, 0); av[mi][1] = lda(cb, 1, mi, 1); }
    STG2(B2, cb, 1, t2);
    BAR; LGKM0;
    MFMA_Q2(1, 1);
    BAR;

#pragma unroll
    for (int nj = 0; nj < 2; ++nj) { bv[nj][0] = ldb(cb, 0, nj, 0); bv[nj][1] = ldb(cb, 0, nj, 1); }
    STG2(A2, cb, 1, t2);
    VM6;
    BAR; LGKM0;
    MFMA_Q2(1, 0);
    BAR;
  }

#pragma unroll
  for (int mh = 0; mh < 2; ++mh)
#pragma unroll
    for (int mi = 0; mi < 4; ++mi)
#pragma unroll
      for (int nh = 0; nh < 2; ++nh)
#pragma unroll
        for (int nj = 0; nj < 2; ++nj) {
          const f32x4 a = acc[mh * 4 + mi][nh * 2 + nj];
          const int col = n0 + wc * 32 + nh * 128 + nj * 16 + fr;
#pragma unroll
          for (int rr = 0; rr < 4; ++rr) {
            const int row = m0 + wr * 64 + mh * 128 + mi * 16 + fg * 4 + rr;
            __builtin_nontemporal_store(a[rr], &O[(size_t)row * HIDDEN + col]);
          }
        }
}

extern "C" void kernel_launch(void* const* d_in, const int* in_sizes, int n_in,
                              void* d_out, int out_size, void* d_ws, size_t ws_size,
                              hipStream_t stream) {
  (void)in_sizes; (void)n_in; (void)out_size; (void)ws_size;
  const float*    x     = (const float*)d_in[0];
  const uint32_t* qw_gu = (const uint32_t*)d_in[1];
  const uint32_t* qz_gu = (const uint32_t*)d_in[2];
  const float*    sc_gu = (const float*)d_in[3];
  const uint32_t* qw_d  = (const uint32_t*)d_in[5];
  const uint32_t* qz_d  = (const uint32_t*)d_in[6];
  const float*    sc_d  = (const float*)d_in[7];
  float*          out   = (float*)d_out;

  char* ws = (char*)d_ws;
  const size_t XB  = (size_t)NTOK * HIDDEN * 2;        // 64 MiB (x f16)
  const size_t W2B = (size_t)HIDDEN * INTER * 2;       // 86 MiB (W2^T bf16)
  const size_t HB  = (size_t)NTOK * INTER * 2;         // 172 MiB (h bf16)
  const size_t SPB = (size_t)32 * WROW * 2 * 4;        // 5.6 MiB spak
  f16*      xb    = (f16*)ws;
  bf16*     wt    = (bf16*)(ws + XB);
  bf16*     hb    = (bf16*)(ws + XB + W2B);
  uint32_t* spakg = (uint32_t*)(ws + XB + W2B + HB);
  uint32_t* repk  = (uint32_t*)(ws + XB + W2B + HB + SPB);  // 43 MiB

  hipFuncSetAttribute((const void*)&gemm1q,
                      hipFuncAttributeMaxDynamicSharedMemorySize, 90112);
  hipFuncSetAttribute((const void*)&gemm8p<INTER, INTER / 64, HIDDEN / 256>,
                      hipFuncAttributeMaxDynamicSharedMemorySize, 131072);

  cvt_f16_kernel<<<NTOK * HIDDEN / 2048, 256, 0, stream>>>(x, xb);
  spak_kernel<<<32 * WROW / 256, 256, 0, stream>>>(qz_gu, sc_gu, spakg);
  repackB_kernel<<<((WROW / 256) * 64 * 2048) / 256, 256, 0, stream>>>(qw_gu, repk);

  gemm1q<<<(WROW / 256) * (NTOK / 256), 512, 90112, stream>>>(xb, repk, spakg, hb);

  dequant_kernel<<<dim3(HIDDEN / 64, (INTER / 8) / 32), 256, 0, stream>>>(
      qw_d, qz_d, sc_d, wt, HIDDEN, INTER);
  gemm8p<INTER, INTER / 64, HIDDEN / 256>
      <<<(HIDDEN / 256) * (NTOK / 256), 512, 131072, stream>>>(hb, wt, out);
}

// Round 12
// 2034.493 us; speedup vs baseline: 1.1275x; 1.0246x over previous
//
#include <hip/hip_runtime.h>
#include <stdint.h>

#define HIDDEN 4096
#define INTER  11008
#define NTOK   8192   // B*S = 4*2048
#define WROW   22016  // 2*INTER, qw_gu row length in u32

typedef __bf16 bf16;
typedef __bf16 bf16x8 __attribute__((ext_vector_type(8)));
typedef _Float16 f16;
typedef _Float16 f16x2 __attribute__((ext_vector_type(2)));
typedef _Float16 f16x8 __attribute__((ext_vector_type(8)));
typedef float  f32x4  __attribute__((ext_vector_type(4)));
typedef unsigned int u32x4 __attribute__((ext_vector_type(4)));

__device__ __forceinline__ void gload16(const void* g, void* l) {
  __builtin_amdgcn_global_load_lds(
      (const __attribute__((address_space(1))) void*)g,
      (__attribute__((address_space(3))) void*)l, 16, 0, 0);
}
__device__ __forceinline__ void gload4(const void* g, void* l) {
  __builtin_amdgcn_global_load_lds(
      (const __attribute__((address_space(1))) void*)g,
      (__attribute__((address_space(3))) void*)l, 4, 0, 0);
}

// ---------------- x: f32 -> f16, k-axis sigma-permuted within each 8 --------
// out order per 8-block: [x0,x4,x1,x5,x2,x6,x3,x7]  (matches cheap B unpack)
__global__ __launch_bounds__(256) void cvt_f16_kernel(const float* __restrict__ x,
                                                      f16* __restrict__ y) {
  const int i = (blockIdx.x * 256 + threadIdx.x) * 8;
  f32x4 a = *(const f32x4*)(x + i);
  f32x4 b = *(const f32x4*)(x + i + 4);
  f16x8 v;
#pragma unroll
  for (int j = 0; j < 4; ++j) { v[2 * j] = (f16)a[j]; v[2 * j + 1] = (f16)b[j]; }
  *(f16x8*)(y + i) = v;
}

// ---------------- spak: per (group, interleaved-col) (s2, k2) f16x2 pairs ----
// layout: u32 spak[(g*22016 + n)*2 + {0: (s,s), 1: (1025+z, 1025+z)}]
__global__ __launch_bounds__(256) void spak_kernel(const uint32_t* __restrict__ qz,
                                                   const float* __restrict__ sc,
                                                   uint32_t* __restrict__ outp) {
  const int idx = blockIdx.x * 256 + threadIdx.x;  // g*22016 + n
  const int gq = idx / WROW;
  const int n = idx - gq * WROW;
  const int grp = n >> 5, win = n & 31;
  const int jg = (win < 16) ? grp * 16 + win : INTER + grp * 16 + (win - 16);
  const float s = sc[(size_t)gq * WROW + jg];
  const uint32_t z = (qz[(size_t)gq * (WROW / 8) + (jg >> 3)] >> ((jg & 7) * 4)) & 15u;
  union { f16 h[2]; uint32_t u; } a, b;
  a.h[0] = (f16)s; a.h[1] = (f16)s;
  b.h[0] = (f16)(float)(1025u + z); b.h[1] = b.h[0];
  outp[(size_t)idx * 2 + 0] = a.u;
  outp[(size_t)idx * 2 + 1] = b.u;
}

// ---------------- B repack: qw_gu -> per (nb, kt) blocks, 4 words/lane ------
// out[nb][kt][c], c = L*4 + j, L = block-thread 0..511 (w = L>>6, fg=(L>>4)&3,
// fr = L&15), j = kk*2 + nj. word = qw[row][jg] with row = kt*8 + kk*4 + fg,
// col = w*32 + nj*16 + fr, n = nb*256+col -> interleaved jg.
__global__ __launch_bounds__(256) void repackB_kernel(const uint32_t* __restrict__ qw,
                                                      uint32_t* __restrict__ outp) {
  const size_t idx = (size_t)blockIdx.x * 256 + threadIdx.x;
  const int c = (int)(idx & 2047);
  const int kt = (int)((idx >> 11) & 63);
  const int nb = (int)(idx >> 17);
  const int j = c & 3;
  const int L = c >> 2;
  const int w = L >> 6, fg = (L >> 4) & 3, fr = L & 15;
  const int kk = j >> 1, nj = j & 1;
  const int row = kt * 8 + kk * 4 + fg;
  const int col = w * 32 + nj * 16 + fr;
  const int n = nb * 256 + col;
  const int grp = n >> 5, win = n & 31;
  const int jg = (win < 16) ? grp * 16 + win : INTER + grp * 16 + (win - 16);
  outp[idx] = qw[(size_t)row * WROW + jg];
}

// ---------------- GPTQ dequant (W2) -> W^T [J][Kout] bf16 (unchanged) -------
__global__ __launch_bounds__(256) void dequant_kernel(const uint32_t* __restrict__ qw,
                                                      const uint32_t* __restrict__ qz,
                                                      const float* __restrict__ sc,
                                                      bf16* __restrict__ out,
                                                      int J, int Kout) {
  __shared__ __align__(16) bf16 T[64 * 256];
  const int tid = threadIdx.x;
  const int tx = tid & 63, ty = tid >> 6;
  const int j0 = blockIdx.x * 64, r0 = blockIdx.y * 32;
  const int j = j0 + tx;
  const int J8 = J >> 3;
#pragma unroll
  for (int i = 0; i < 8; ++i) {
    const int r = r0 + ty * 8 + i;
    const int g = r >> 4;
    const uint32_t w = qw[(size_t)r * J + j];
    const float s = sc[(size_t)g * J + j];
    const uint32_t zb = (qz[(size_t)g * J8 + (j >> 3)] >> ((j & 7) * 4)) & 15u;
    const float zoff = (float)(zb + 1u);
    bf16x8 v;
#pragma unroll
    for (int e = 0; e < 8; ++e) {
      const float wv = (float)((w >> (e * 4)) & 15u);
      v[e] = (bf16)(s * (wv - zoff));
    }
    const int lb = (tx * 512 + (ty * 8 + i) * 16) ^ ((tx & 31) << 4);
    *(bf16x8*)((char*)T + lb) = v;
  }
  __syncthreads();
#pragma unroll
  for (int u = 0; u < 8; ++u) {
    const int unit = u * 256 + tid;
    const int jj = unit >> 5;
    const int ob = (unit & 31) * 16;
    const int lb = (jj * 512 + ob) ^ ((jj & 31) << 4);
    bf16x8 v = *(const bf16x8*)((const char*)T + lb);
    *(bf16x8*)(out + (size_t)(j0 + jj) * Kout + r0 * 8 + (ob >> 1)) = v;
  }
}

// ============================================================================
//  GEMM1 (fused 4-bit dequant, tall-wave): H = silu(x@Wg)*(x@Wu)
//  Each wave owns 256M x 32N (one interleave group). Per tile: 4 B-word
//  unpacks/wave (half of old 2-wr layout), 64 MFMA, 32+1 b128 ds reads.
//  LDS: A dbuf 2x32KB @0, B dbuf 2x8KB @65536, spak 4x2KB @81920. 88 KiB.
//  Sync/vmcnt skeleton IDENTICAL to the verified R11 kernel.
// ============================================================================
#define OFF_BP 65536
#define OFF_SPK 81920

#define BAR __builtin_amdgcn_s_barrier()
#define LGKM0                                              \
  do {                                                     \
    asm volatile("s_waitcnt lgkmcnt(0)" ::: "memory");     \
    __builtin_amdgcn_sched_barrier(0);                     \
  } while (0)
#define VM2 asm volatile("s_waitcnt vmcnt(2)" ::: "memory")
#define VM3 asm volatile("s_waitcnt vmcnt(3)" ::: "memory")

#define STG_A(buf, h, tt)                                                      \
  do {                                                                         \
    gload16(sA00 + ((size_t)((h) * 128) * (HIDDEN * 2)) + (size_t)(tt) * 128,  \
            lds + (buf) * 32768 + (h) * 16384 + w * 1024);                     \
    gload16(sA00 + ((size_t)((h) * 128 + 64) * (HIDDEN * 2)) + (size_t)(tt) * 128, \
            lds + (buf) * 32768 + (h) * 16384 + 8192 + w * 1024);              \
  } while (0)

#define STG_B(buf, tt)                                                         \
  gload16(repk_src + (size_t)(tt) * 2048 + tid * 4,                            \
          lds + OFF_BP + (buf) * 8192 + tid * 16)

#define STG_SPK(gt)                                                           \
  gload4(spakg + ((size_t)(gt) * WROW + n0) * 2 + tid,                        \
         lds + OFF_SPK + ((gt) & 3) * 2048 + w * 256)

// sigma unpack: pairs (n0,n4),(n1,n5),(n2,n6),(n3,n7); exact until final mul
__device__ __forceinline__ f16x8 unpack8s(uint32_t u, f16x2 s2, f16x2 k2) {
  const uint32_t MSK = 0x000F000Fu, M = 0x64006400u;
  uint32_t q0 = (u & MSK) | M;
  uint32_t q1 = ((u >> 4) & MSK) | M;
  uint32_t q2 = ((u >> 8) & MSK) | M;
  uint32_t q3 = ((u >> 12) & MSK) | M;
  f16x2 w0 = (__builtin_bit_cast(f16x2, q0) - k2) * s2;
  f16x2 w1 = (__builtin_bit_cast(f16x2, q1) - k2) * s2;
  f16x2 w2 = (__builtin_bit_cast(f16x2, q2) - k2) * s2;
  f16x2 w3 = (__builtin_bit_cast(f16x2, q3) - k2) * s2;
  f16x8 r;
  r[0] = w0[0]; r[1] = w0[1]; r[2] = w1[0]; r[3] = w1[1];
  r[4] = w2[0]; r[5] = w2[1]; r[6] = w3[0]; r[7] = w3[1];
  return r;
}

#define MFMA4(R, NJ, KK)                                                       \
  _Pragma("unroll") for (int mi = 0; mi < 4; ++mi)                             \
      acc[(R) + mi][NJ] = __builtin_amdgcn_mfma_f32_16x16x32_f16(              \
          av[mi][KK], bv[NJ][KK], acc[(R) + mi][NJ], 0, 0, 0)

#define MFMA16(R)                                                              \
  _Pragma("unroll") for (int kk = 0; kk < 2; ++kk)                             \
    _Pragma("unroll") for (int nj = 0; nj < 2; ++nj)                           \
      _Pragma("unroll") for (int mi = 0; mi < 4; ++mi)                         \
          acc[(R) + mi][nj] = __builtin_amdgcn_mfma_f32_16x16x32_f16(          \
              av[mi][kk], bv[nj][kk], acc[(R) + mi][nj], 0, 0, 0)

__global__ __launch_bounds__(512, 2) void gemm1q(const f16* __restrict__ A,
                                                 const uint32_t* __restrict__ repk,
                                                 const uint32_t* __restrict__ spakg,
                                                 bf16* __restrict__ H) {
  extern __shared__ char lds[];
  const int tid = threadIdx.x;
  const int lane = tid & 63, w = tid >> 6;
  const int fr = lane & 15, fg = lane >> 4;
  constexpr int NT = HIDDEN / 64;  // 64 K-tiles, 32 groups

  const int wg = blockIdx.x;
  const int nb = wg % (WROW / 256), mb = wg / (WROW / 256);
  const int m0 = mb << 8, n0 = nb << 8;

  // ---- A stage base (other 3 ptrs are compile-time offsets)
  const int rbase = tid >> 3;                 // 0..63
  const int cbyte0 = (tid & 7) * 16;
  const int cL0 = cbyte0 ^ ((rbase & 7) << 4);
  const char* sA00 = (const char*)A + (size_t)(m0 + rbase) * (size_t)(HIDDEN * 2) + cL0;

  // ---- B stage source: linear repacked block for this nb
  const uint32_t* repk_src = repk + (size_t)nb * 64 * 2048;

  // ---- fragment read offsets (tall-wave: rows mi*16 + fr, mi 0..15)
  const int swz = (fr & 7) << 4;
  const int ck[2] = {(fg * 16) ^ swz, (64 + fg * 16) ^ swz};
  const int aro = fr * 128;
  auto lda = [&](int buf, int mi, int kk) -> f16x8 {
    return *(const f16x8*)(lds + buf * 32768 + mi * 2048 + aro + ck[kk]);
  };
  const int ncol2[2] = {w * 32 + fr, w * 32 + 16 + fr};  // [nj]

  f32x4 acc[16][2];
#pragma unroll
  for (int i = 0; i < 16; ++i)
#pragma unroll
    for (int j = 0; j < 2; ++j) acc[i][j] = (f32x4)0.0f;
  f16x8 av[4][2], bv[2][2];
  f16x2 s2r[2], k2r[2];

  // ---- prologue: queue [spk0, A0,A0, B, A1,A1]; drain first 4
  STG_SPK(0);
  STG_A(0, 0, 0);
  STG_B(0, 0);
  STG_A(0, 1, 0);
  VM2;
  BAR;

  for (int t = 0; t < NT; ++t) {
    const int cb = t & 1, nx = cb ^ 1, g = t >> 1;
    const int t1 = (t + 1 < NT) ? t + 1 : 0;  // dummy keeps vmcnt exact

    // ======== ph1: av mi0..3 + B b128 (+spak even-t); stage A0,B -> nx;
    //          unpack 4 words; MFMA mi0..7 ========
#pragma unroll
    for (int mi = 0; mi < 4; ++mi) { av[mi][0] = lda(cb, mi, 0); av[mi][1] = lda(cb, mi, 1); }
    u32x4 vv = *(const u32x4*)(lds + OFF_BP + cb * 8192 + tid * 16);
    if ((t & 1) == 0) {
      const char* sp = lds + OFF_SPK + (g & 3) * 2048;
#pragma unroll
      for (int nj = 0; nj < 2; ++nj) {
        s2r[nj] = *(const f16x2*)(sp + ncol2[nj] * 8);
        k2r[nj] = *(const f16x2*)(sp + ncol2[nj] * 8 + 4);
      }
    }
    STG_A(nx, 0, t1);
    STG_B(nx, t1);
    VM3;   // drains prev-tile A1 pair (+spak) -> ph2 inputs ready
    BAR; LGKM0;
    __builtin_amdgcn_s_setprio(1);
    bv[0][0] = unpack8s(vv.x, s2r[0], k2r[0]);
    MFMA4(0, 0, 0);
    bv[1][0] = unpack8s(vv.y, s2r[1], k2r[1]);
    MFMA4(0, 1, 0);
    bv[0][1] = unpack8s(vv.z, s2r[0], k2r[0]);
    MFMA4(0, 0, 1);
    bv[1][1] = unpack8s(vv.w, s2r[1], k2r[1]);
    MFMA4(0, 1, 1);
    __builtin_amdgcn_s_setprio(0);
    __builtin_amdgcn_sched_barrier(0);
    // group 2: av mi4..7 into same regs, 16 MFMA
#pragma unroll
    for (int mi = 0; mi < 4; ++mi) { av[mi][0] = lda(cb, 4 + mi, 0); av[mi][1] = lda(cb, 4 + mi, 1); }
    LGKM0;
    __builtin_amdgcn_s_setprio(1);
    MFMA16(4);
    __builtin_amdgcn_s_setprio(0);
    __builtin_amdgcn_sched_barrier(0);
    BAR;

    // ======== ph2: av mi8..15 (two groups); [odd: spak first] + stage A1;
    //          pure MFMA (bv persists) ========
#pragma unroll
    for (int mi = 0; mi < 4; ++mi) { av[mi][0] = lda(cb, 8 + mi, 0); av[mi][1] = lda(cb, 8 + mi, 1); }
    if (t & 1) {
      const int gt = (g + 1 < 32) ? g + 1 : 31;
      STG_SPK(gt);   // FIRST in ph2 queue so end-of-tile VM2 drains it
    }
    STG_A(nx, 1, t1);
    BAR; LGKM0;
    __builtin_amdgcn_s_setprio(1);
    MFMA16(8);
    __builtin_amdgcn_s_setprio(0);
    __builtin_amdgcn_sched_barrier(0);
#pragma unroll
    for (int mi = 0; mi < 4; ++mi) { av[mi][0] = lda(cb, 12 + mi, 0); av[mi][1] = lda(cb, 12 + mi, 1); }
    LGKM0;
    __builtin_amdgcn_s_setprio(1);
    MFMA16(12);
    __builtin_amdgcn_s_setprio(0);
    __builtin_amdgcn_sched_barrier(0);
    VM2;   // drains A0,B(,spk) for next ph1; leaves next A1 pair in flight
    BAR;
  }
  asm volatile("s_waitcnt vmcnt(0)" ::: "memory");

  // ---- epilogue: h = silu(g)*u -> bf16 (wave col group fixed)
  const int col = (n0 >> 1) + w * 16 + fr;
#pragma unroll
  for (int mi = 0; mi < 16; ++mi) {
    const f32x4 gv4 = acc[mi][0];
    const f32x4 uv4 = acc[mi][1];
#pragma unroll
    for (int rr = 0; rr < 4; ++rr) {
      const int row = m0 + mi * 16 + fg * 4 + rr;
      const float gv = gv4[rr], uv = uv4[rr];
      H[(size_t)row * INTER + col] = (bf16)(gv / (1.0f + __expf(-gv)) * uv);
    }
  }
}

// ---------------- GEMM2: 256x256 8-phase bf16 (unchanged, working) ----------
#define OFF_A2 0
#define OFF_B2 32768

#define STG2(mat, buf, h, t)                                                   \
  do {                                                                         \
    gload16(s##mat[h][0] + (size_t)(t) * 128,                                  \
            lds + (buf) * 65536 + OFF_##mat + (h) * 16384 + w * 1024);         \
    gload16(s##mat[h][1] + (size_t)(t) * 128,                                  \
            lds + (buf) * 65536 + OFF_##mat + (h) * 16384 + 8192 + w * 1024);  \
  } while (0)
#define VM6 asm volatile("s_waitcnt vmcnt(6)" ::: "memory")

#define MFMA_Q2(MH, NH)                                                        \
  do {                                                                         \
    __builtin_amdgcn_s_setprio(1);                                             \
    _Pragma("unroll") for (int kk = 0; kk < 2; ++kk) {                         \
      _Pragma("unroll") for (int nj = 0; nj < 2; ++nj) {                       \
        _Pragma("unroll") for (int mi = 0; mi < 4; ++mi) {                     \
          acc[(MH)*4 + mi][(NH)*2 + nj] = __builtin_amdgcn_mfma_f32_16x16x32_bf16( \
              av[mi][kk], bv[nj][kk], acc[(MH)*4 + mi][(NH)*2 + nj], 0, 0, 0); \
        }                                                                      \
      }                                                                        \
    }                                                                          \
    __builtin_amdgcn_s_setprio(0);                                             \
    __builtin_amdgcn_sched_barrier(0);                                         \
  } while (0)

template <int K, int NT, int NNB>
__global__ __launch_bounds__(512, 2) void gemm8p(const bf16* __restrict__ A,
                                                 const bf16* __restrict__ Bm,
                                                 float* __restrict__ O) {
  extern __shared__ char lds[];
  const int tid = threadIdx.x;
  const int lane = tid & 63, w = tid >> 6;
  const int wr = w >> 2, wc = w & 3;
  const int fr = lane & 15, fg = lane >> 4;

  const int wg = blockIdx.x;
  const int nb = wg % NNB, mb = wg / NNB;
  const int m0 = mb << 8, n0 = nb << 8;

  const char* sA2[2][2];
  const char* sB2[2][2];
#pragma unroll
  for (int h = 0; h < 2; ++h)
#pragma unroll
    for (int l = 0; l < 2; ++l) {
      const int d = h * 16384 + (l * 512 + tid) * 16;
      const int r = d >> 7;
      const int cL = (d & 127) ^ ((r & 7) << 4);
      sA2[h][l] = (const char*)A + (size_t)(m0 + r) * (size_t)(K * 2) + cL;
      sB2[h][l] = (const char*)Bm + (size_t)(n0 + r) * (size_t)(K * 2) + cL;
    }

  const int swz = (fr & 7) << 4;
  const int ck[2] = {(fg * 16) ^ swz, (64 + fg * 16) ^ swz};
  const int aro = (wr * 64 + fr) * 128;
  const int bro = OFF_B2 + (wc * 32 + fr) * 128;

  auto lda = [&](int buf, int mh, int mi, int kk) -> bf16x8 {
    return *(const bf16x8*)(lds + buf * 65536 + mh * 16384 + aro + mi * 2048 + ck[kk]);
  };
  auto ldb = [&](int buf, int nh, int nj, int kk) -> bf16x8 {
    return *(const bf16x8*)(lds + buf * 65536 + bro + nh * 16384 + nj * 2048 + ck[kk]);
  };

  f32x4 acc[8][4];
#pragma unroll
  for (int i = 0; i < 8; ++i)
#pragma unroll
    for (int j = 0; j < 4; ++j) acc[i][j] = (f32x4)0.0f;
  bf16x8 av[4][2], bv[2][2];

  STG2(A2, 0, 0, 0);
  STG2(B2, 0, 0, 0);
  STG2(B2, 0, 1, 0);
  STG2(A2, 0, 1, 0);
  STG2(A2, 1, 0, 1);
  STG2(B2, 1, 1, 1);
  STG2(A2, 1, 1, 1);
  VM6;
  BAR;

  for (int t = 0; t < NT; ++t) {
    const int cb = t & 1, nx = cb ^ 1;
    const int t1 = (t + 1 < NT) ? t + 1 : 0;
    const int t2 = (t + 2 < NT) ? t + 2 : 0;

#pragma unroll
    for (int mi = 0; mi < 4; ++mi) { av[mi][0] = lda(cb, 0, mi, 0); av[mi][1] = lda(cb, 0, mi, 1); }
#pragma unroll
    for (int nj = 0; nj < 2; ++nj) { bv[nj][0] = ldb(cb, 0, nj, 0); bv[nj][1] = ldb(cb, 0, nj, 1); }
    STG2(B2, nx, 0, t1);
    BAR; LGKM0;
    MFMA_Q2(0, 0);
    BAR;

#pragma unroll
    for (int nj = 0; nj < 2; ++nj) { bv[nj][0] = ldb(cb, 1, nj, 0); bv[nj][1] = ldb(cb, 1, nj, 1); }
    STG2(A2, cb, 0, t2);
    BAR; LGKM0;
    MFMA_Q2(0, 1);
    BAR;

#pragma unroll
    for (int mi = 0; mi < 4; ++mi) { av[mi][0] = lda(cb, 1, mi, 0); av[mi][1] = lda(cb, 1, mi, 1); }
    STG2(B2, cb, 1, t2);
    BAR; LGKM0;
    MFMA_Q2(1, 1);
    BAR;

#pragma unroll
    for (int nj = 0; nj < 2; ++nj) { bv[nj][0] = ldb(cb, 0, nj, 0); bv[nj][1] = ldb(cb, 0, nj, 1); }
    STG2(A2, cb, 1, t2);
    VM6;
    BAR; LGKM0;
    MFMA_Q2(1, 0);
    BAR;
  }

#pragma unroll
  for (int mh = 0; mh < 2; ++mh)
#pragma unroll
    for (int mi = 0; mi < 4; ++mi)
#pragma unroll
      for (int nh = 0; nh < 2; ++nh)
#pragma unroll
        for (int nj = 0; nj < 2; ++nj) {
          const f32x4 a = acc[mh * 4 + mi][nh * 2 + nj];
          const int col = n0 + wc * 32 + nh * 128 + nj * 16 + fr;
#pragma unroll
          for (int rr = 0; rr < 4; ++rr) {
            const int row = m0 + wr * 64 + mh * 128 + mi * 16 + fg * 4 + rr;
            __builtin_nontemporal_store(a[rr], &O[(size_t)row * HIDDEN + col]);
          }
        }
}

extern "C" void kernel_launch(void* const* d_in, const int* in_sizes, int n_in,
                              void* d_out, int out_size, void* d_ws, size_t ws_size,
                              hipStream_t stream) {
  (void)in_sizes; (void)n_in; (void)out_size; (void)ws_size;
  const float*    x     = (const float*)d_in[0];
  const uint32_t* qw_gu = (const uint32_t*)d_in[1];
  const uint32_t* qz_gu = (const uint32_t*)d_in[2];
  const float*    sc_gu = (const float*)d_in[3];
  const uint32_t* qw_d  = (const uint32_t*)d_in[5];
  const uint32_t* qz_d  = (const uint32_t*)d_in[6];
  const float*    sc_d  = (const float*)d_in[7];
  float*          out   = (float*)d_out;

  char* ws = (char*)d_ws;
  const size_t XB  = (size_t)NTOK * HIDDEN * 2;        // 64 MiB (x f16)
  const size_t W2B = (size_t)HIDDEN * INTER * 2;       // 86 MiB (W2^T bf16)
  const size_t HB  = (size_t)NTOK * INTER * 2;         // 172 MiB (h bf16)
  const size_t SPB = (size_t)32 * WROW * 2 * 4;        // 5.6 MiB spak
  f16*      xb    = (f16*)ws;
  bf16*     wt    = (bf16*)(ws + XB);
  bf16*     hb    = (bf16*)(ws + XB + W2B);
  uint32_t* spakg = (uint32_t*)(ws + XB + W2B + HB);
  uint32_t* repk  = (uint32_t*)(ws + XB + W2B + HB + SPB);  // 43 MiB

  hipFuncSetAttribute((const void*)&gemm1q,
                      hipFuncAttributeMaxDynamicSharedMemorySize, 90112);
  hipFuncSetAttribute((const void*)&gemm8p<INTER, INTER / 64, HIDDEN / 256>,
                      hipFuncAttributeMaxDynamicSharedMemorySize, 131072);

  cvt_f16_kernel<<<NTOK * HIDDEN / 2048, 256, 0, stream>>>(x, xb);
  spak_kernel<<<32 * WROW / 256, 256, 0, stream>>>(qz_gu, sc_gu, spakg);
  repackB_kernel<<<((WROW / 256) * 64 * 2048) / 256, 256, 0, stream>>>(qw_gu, repk);

  gemm1q<<<(WROW / 256) * (NTOK / 256), 512, 90112, stream>>>(xb, repk, spakg, hb);

  dequant_kernel<<<dim3(HIDDEN / 64, (INTER / 8) / 32), 256, 0, stream>>>(
      qw_d, qz_d, sc_d, wt, HIDDEN, INTER);
  gemm8p<INTER, INTER / 64, HIDDEN / 256>
      <<<(HIDDEN / 256) * (NTOK / 256), 512, 131072, stream>>>(hb, wt, out);
}